// Round 12
// baseline (452.227 us; speedup 1.0000x reference)
//
#include <hip/hip_runtime.h>
#include <math.h>

#define GRIDN 64
#define MAXE 32
#define MAXPRIM 1024
#define EROW 36        // parent row: [cnt, e0..e31, pad x3]
#define SCAP2 15
#define SENTV 0xFFFF
#define LUTN 1024

// workspace layout (bytes)
#define WS_PACKED2   0u            // 1024*32
#define WS_COLORS    32768u        // 1024*16
#define WS_ETAB      49152u        // 4096*36*4 -> ends 638976
#define WS_FLAGS     638976u       // 4 ints: [0] opac!=1, [1] parent-trunc, [2] sentinel count
#define WS_SUBTAB    655360u       // 65536*32 = 2 MB -> ends 2752512
#define WS_LUT       2752512u      // 1024*1024*2 = 2 MB -> ends 4849664
#define WS_LIST      4849664u      // npts*4

// exact core: t = rn(td/denom) (double-recip mul), s2 <= Tf <=> rn(sqrt(s2)) <= w
#define CORE_EVAL(A, Bv)                                                         \
    float relx = __fsub_rn(px, A.x);                                             \
    float rely = __fsub_rn(py, A.y);                                             \
    float td = __fadd_rn(__fmul_rn(relx, A.z), __fmul_rn(rely, A.w));            \
    double inv = __hiloint2double(__float_as_int(Bv.z), __float_as_int(Bv.y));   \
    float tt = (float)((double)td * inv);                                        \
    tt = fminf(fmaxf(tt, 0.0f), 1.0f);                                           \
    float qx = __fsub_rn(relx, __fmul_rn(tt, A.z));                              \
    float qy = __fsub_rn(rely, __fmul_rn(tt, A.w));                              \
    float s2 = __fadd_rn(__fmul_rn(qx, qx), __fmul_rn(qy, qy));

// ---------------------------------------------------------------------------
// Kernel 1 (fused): parent grid build + subgrid prune + (block 0) prim pack.
// flags[1] set if any parent list would be truncated (disables LUT validity).
// ---------------------------------------------------------------------------
__global__ __launch_bounds__(1024) void prep2(const float* __restrict__ cp,
                                              const float* __restrict__ sw,
                                              const float* __restrict__ fc,
                                              const float* __restrict__ op,
                                              float4* __restrict__ packed2,
                                              float4* __restrict__ colors,
                                              int* __restrict__ etab,
                                              int* __restrict__ flags,
                                              unsigned short* __restrict__ subtab,
                                              int nprim, int do_sub) {
    __shared__ float4 saabb[MAXPRIM];
    __shared__ float4 sseg[MAXPRIM];   // (x0, y0, dx, dy)
    __shared__ float  sww[MAXPRIM];
    __shared__ int    srows[16][EROW];
    int tid = threadIdx.x;
    for (int p = tid; p < nprim; p += 1024) {
        float x0 = cp[p * 6 + 0], y0 = cp[p * 6 + 1];
        float x1 = cp[p * 6 + 2], y1 = cp[p * 6 + 3];
        float w = sw[p];
        saabb[p] = make_float4(__fsub_rn(fminf(x0, x1), w), __fadd_rn(fmaxf(x0, x1), w),
                               __fsub_rn(fminf(y0, y1), w), __fadd_rn(fmaxf(y0, y1), w));
        sseg[p] = make_float4(x0, y0, __fsub_rn(x1, x0), __fsub_rn(y1, y0));
        sww[p] = w;
    }
    __syncthreads();

    // ---- phase B: parent rows (one wave per parent cell) ----
    int wid = tid >> 6, lane = tid & 63;
    int cell = blockIdx.x * 16 + wid;
    {
        int ixc = cell >> 6, iyc = cell & 63;
        float lox = (float)ixc * (1.0f / GRIDN);
        float hix = (float)(ixc + 1) * (1.0f / GRIDN);
        float loy = (float)iyc * (1.0f / GRIDN);
        float hiy = (float)(iyc + 1) * (1.0f / GRIDN);
        int total = 0;
        int* row = etab + (size_t)cell * EROW;
        for (int base = 0; base < nprim; base += 64) {
            int p = base + lane;
            bool ov = false;
            if (p < nprim) {
                float4 bb = saabb[p];
                ov = (bb.x < hix) && (bb.y >= lox) && (bb.z < hiy) && (bb.w >= loy);
            }
            unsigned long long m = __ballot(ov);
            if (ov) {
                int pos = total + (int)__popcll(m & ((1ull << lane) - 1ull));
                if (pos < MAXE) { row[1 + pos] = p; srows[wid][1 + pos] = p; }
            }
            total += (int)__popcll(m);
        }
        if (lane == 0) {
            int c = total < MAXE ? total : MAXE;
            row[0] = c;
            srows[wid][0] = c;
            if (total > MAXE) atomicOr(&flags[1], 1);
        }
    }
    __syncthreads();

    // ---- phase C: subcell pruning (threads 0-255, one subcell each) ----
    if (do_sub && tid < 256) {
        int lp = tid >> 4;
        int sub = tid & 15;
        int pcell = blockIdx.x * 16 + lp;
        int ix = pcell >> 6, iy = pcell & 63;
        int gx = ix * 4 + (sub >> 2), gy = iy * 4 + (sub & 3);
        double clx = (double)gx * (1.0 / 256.0);
        double chx = (double)(gx + 1) * (1.0 / 256.0);
        double cly = (double)gy * (1.0 / 256.0);
        double chy = (double)(gy + 1) * (1.0 / 256.0);
        int cnt = srows[lp][0];
        unsigned short* srow = subtab + (size_t)(gx * 256 + gy) * 16;
        int oc = 0;
        for (int s = 0; s < cnt; ++s) {
            int e = srows[lp][1 + s];
            float4 A = sseg[e];
            double W = (double)sww[e] + 1e-5;
            double lx = clx - W, hx = chx + W, ly = cly - W, hy = chy + W;
            double ax = (double)A.x, ay = (double)A.y;
            double dx = (double)A.z, dy = (double)A.w;
            double t0 = 0.0, t1 = 1.0;
            bool ok = true;
            if (fabs(dx) > 1e-300) {
                double ta = (lx - ax) / dx, tb = (hx - ax) / dx;
                t0 = fmax(t0, fmin(ta, tb));
                t1 = fmin(t1, fmax(ta, tb));
            } else if (ax < lx || ax > hx) ok = false;
            if (ok) {
                if (fabs(dy) > 1e-300) {
                    double ta = (ly - ay) / dy, tb = (hy - ay) / dy;
                    t0 = fmax(t0, fmin(ta, tb));
                    t1 = fmin(t1, fmax(ta, tb));
                } else if (ay < ly || ay > hy) ok = false;
            }
            if (ok && t0 <= t1) {
                if (oc < SCAP2) srow[1 + oc] = (unsigned short)e;
                ++oc;
            }
        }
        int filled = oc < SCAP2 ? oc : SCAP2;
        for (int k = filled; k < SCAP2; ++k) srow[1 + k] = 0;
        srow[0] = (oc <= SCAP2) ? (unsigned short)oc : (unsigned short)SENTV;
    }

    // ---- phase D: prim pack (block 0) ----
    if (blockIdx.x == 0) {
        bool bad = false;
        for (int p = tid; p < nprim; p += 1024) {
            float x0 = cp[p * 6 + 0], y0 = cp[p * 6 + 1];
            float x1 = cp[p * 6 + 2], y1 = cp[p * 6 + 3];
            float w = sw[p];
            float dx = __fsub_rn(x1, x0);
            float dy = __fsub_rn(y1, y0);
            float dd = __fadd_rn(__fmul_rn(dx, dx), __fmul_rn(dy, dy));
            float denom = fmaxf(dd, 1e-12f);
            double inv = 1.0 / (double)denom;
            unsigned wb = __float_as_uint(w);
            bool even = (wb & 1u) == 0u;
            float wn = __uint_as_float(wb + 1u);
            double md = 0.5 * ((double)w + (double)wn);
            double m2 = md * md;
            float Tf = (float)m2;
            if ((double)Tf > m2) Tf = __uint_as_float(__float_as_uint(Tf) - 1u);
            if (!even && (double)Tf == m2) Tf = __uint_as_float(__float_as_uint(Tf) - 1u);
            unsigned long long ib = __double_as_longlong(inv);
            packed2[p * 2 + 0] = make_float4(x0, y0, dx, dy);
            packed2[p * 2 + 1] = make_float4(Tf,
                                             __uint_as_float((unsigned)(ib & 0xffffffffull)),
                                             __uint_as_float((unsigned)(ib >> 32)),
                                             w);
            float opv = op[p];
            colors[p] = make_float4(fc[p * 3 + 0], fc[p * 3 + 1], fc[p * 3 + 2], opv);
            if (opv != 1.0f) bad = true;
        }
        if (bad) atomicOr(&flags[0], 1);
    }
}

// ---------------------------------------------------------------------------
// Kernel 2: classify 1024x1024 pixel LUT. Per pixel: descending scan of its
// subcell candidate list; tri-state per candidate (f64, conservative margins):
//   outside: capsule(w+1e-5) slab-test misses pixel rect (expanded 1e-6)
//   inside:  all 4 corners true-dist <= w-1e-5 (max over rect at corners,
//            distance-to-segment is convex)
//   else ambiguous -> sentinel.
// First fully-inside (highest index) wins; ambiguous above it -> sentinel.
// lut: 0 = background, e+1 = prim winner, 0xFFFF = exact path.
// ---------------------------------------------------------------------------
__global__ __launch_bounds__(256) void classify(const float4* __restrict__ packed2,
                                                const unsigned short* __restrict__ subtab,
                                                const int* __restrict__ flags,
                                                unsigned short* __restrict__ lut) {
    int pi = blockIdx.x * 256 + threadIdx.x;     // 4096 blocks x 256 = 1M pixels
    int pix = pi >> 10, piy = pi & 1023;
    if ((flags[0] | flags[1]) != 0) { lut[pi] = (unsigned short)SENTV; return; }
    const unsigned short* sr = subtab + (size_t)((pix >> 2) * 256 + (piy >> 2)) * 16;
    int cnt = sr[0];
    if (cnt == (int)SENTV) { lut[pi] = (unsigned short)SENTV; return; }
    double plx = (double)pix * (1.0 / LUTN) - 1e-6;
    double phx = (double)(pix + 1) * (1.0 / LUTN) + 1e-6;
    double ply = (double)piy * (1.0 / LUTN) - 1e-6;
    double phy = (double)(piy + 1) * (1.0 / LUTN) + 1e-6;
    unsigned short ans = 0;
    for (int s = cnt - 1; s >= 0; --s) {
        int e = sr[1 + s];
        float4 A = packed2[e * 2 + 0];
        float4 B = packed2[e * 2 + 1];
        double ax = (double)A.x, ay = (double)A.y;
        double dx = (double)A.z, dy = (double)A.w;
        double w = (double)B.w;
        double W = w + 1e-5;
        double lx = plx - W, hx = phx + W, ly = ply - W, hy = phy + W;
        double t0 = 0.0, t1 = 1.0;
        bool ok = true;
        if (fabs(dx) > 1e-300) {
            double ta = (lx - ax) / dx, tb = (hx - ax) / dx;
            t0 = fmax(t0, fmin(ta, tb));
            t1 = fmin(t1, fmax(ta, tb));
        } else if (ax < lx || ax > hx) ok = false;
        if (ok) {
            if (fabs(dy) > 1e-300) {
                double ta = (ly - ay) / dy, tb = (hy - ay) / dy;
                t0 = fmax(t0, fmin(ta, tb));
                t1 = fmin(t1, fmax(ta, tb));
            } else if (ay < ly || ay > hy) ok = false;
        }
        if (!ok || t0 > t1) continue;            // fully outside
        double wm = w - 1e-5;
        bool allin = false;
        if (wm > 0.0) {
            double inv = __hiloint2double(__float_as_int(B.z), __float_as_int(B.y));
            double wm2 = wm * wm;
            allin = true;
#pragma unroll
            for (int c = 0; c < 4; ++c) {
                double cx = (c & 1) ? phx : plx;
                double cy = (c & 2) ? phy : ply;
                double rx = cx - ax, ry = cy - ay;
                double t = (rx * dx + ry * dy) * inv;
                t = fmin(fmax(t, 0.0), 1.0);
                double qx = rx - t * dx, qy = ry - t * dy;
                if (qx * qx + qy * qy > wm2) { allin = false; break; }
            }
        }
        ans = allin ? (unsigned short)(e + 1) : (unsigned short)SENTV;
        break;
    }
    lut[pi] = ans;
}

// ---------------------------------------------------------------------------
// Kernel 3: fast render. Per point: 1 LUT gather -> color (or compact index
// into sentinel list via wave ballot + one atomic per wave).
// ---------------------------------------------------------------------------
__global__ __launch_bounds__(512) void render_fast(const float4* __restrict__ xs4,
                                                   const float4* __restrict__ colors,
                                                   const unsigned short* __restrict__ lut,
                                                   const float* __restrict__ bg,
                                                   int* __restrict__ flags,
                                                   int* __restrict__ slist,
                                                   float* __restrict__ out, int n) {
    int tid = threadIdx.x;
    long long g0 = (long long)blockIdx.x * 1024 + (long long)tid * 2;
    bool v0 = g0 < (long long)n, v1 = (g0 + 1) < (long long)n;

    float4 P = make_float4(0.f, 0.f, 0.f, 0.f);
    if (v1) {
        P = xs4[g0 >> 1];
    } else if (v0) {
        float2 t2 = ((const float2*)xs4)[g0];
        P.x = t2.x; P.y = t2.y;
    }
    int w0 = 0, w1 = 0;
    if (v0) {
        int ipx = (int)__fmul_rn(P.x, (float)LUTN); ipx = min(max(ipx, 0), LUTN - 1);
        int ipy = (int)__fmul_rn(P.y, (float)LUTN); ipy = min(max(ipy, 0), LUTN - 1);
        w0 = lut[ipx * LUTN + ipy];
    }
    if (v1) {
        int ipx = (int)__fmul_rn(P.z, (float)LUTN); ipx = min(max(ipx, 0), LUTN - 1);
        int ipy = (int)__fmul_rn(P.w, (float)LUTN); ipy = min(max(ipy, 0), LUTN - 1);
        w1 = lut[ipx * LUTN + ipy];
    }
    bool s0 = v0 && (w0 == (int)SENTV);
    bool s1 = v1 && (w1 == (int)SENTV);

    float bgr = bg[0], bgg = bg[1], bgb = bg[2];
    if (v0 && !s0) {
        float cr = bgr, cg = bgg, cb = bgb;
        if (w0 > 0) { float4 C = colors[w0 - 1]; cr = C.x; cg = C.y; cb = C.z; }
        float* ob = out + g0 * 3;
        ob[0] = cr; ob[1] = cg; ob[2] = cb;
    }
    if (v1 && !s1) {
        float cr = bgr, cg = bgg, cb = bgb;
        if (w1 > 0) { float4 C = colors[w1 - 1]; cr = C.x; cg = C.y; cb = C.z; }
        float* ob = out + (g0 + 1) * 3;
        ob[0] = cr; ob[1] = cg; ob[2] = cb;
    }

    // wave-level compaction of sentinel point indices
    unsigned long long m0 = __ballot(s0);
    unsigned long long m1 = __ballot(s1);
    int c0 = (int)__popcll(m0);
    int tot = c0 + (int)__popcll(m1);
    int lane = tid & 63;
    int base = 0;
    if (lane == 0 && tot) base = atomicAdd(&flags[2], tot);
    base = __shfl(base, 0);
    unsigned long long lm = (1ull << lane) - 1ull;
    if (s0) slist[base + (int)__popcll(m0 & lm)] = (int)g0;
    if (s1) slist[base + c0 + (int)__popcll(m1 & lm)] = (int)(g0 + 1);
}

// exact per-prim test, global tables
__device__ __forceinline__ void test_g(int e, float px, float py, bool fast,
                                       int& win, float& cr, float& cg, float& cb,
                                       const float4* __restrict__ packed2,
                                       const float4* __restrict__ colors) {
    float4 A = packed2[e * 2 + 0];
    float4 Bv = packed2[e * 2 + 1];
    CORE_EVAL(A, Bv);
    if (fast) {
        if (s2 <= Bv.x) win = e;
    } else {
        float4 C = colors[e];
        float a = (s2 <= Bv.x) ? C.w : 0.0f;
        float om = __fsub_rn(1.0f, a);
        cr = __fadd_rn(__fmul_rn(cr, om), __fmul_rn(C.x, a));
        cg = __fadd_rn(__fmul_rn(cg, om), __fmul_rn(C.y, a));
        cb = __fadd_rn(__fmul_rn(cb, om), __fmul_rn(C.z, a));
    }
}

// ---------------------------------------------------------------------------
// Kernel 4: exact render over the compacted sentinel list (dense lanes).
// ---------------------------------------------------------------------------
__global__ __launch_bounds__(256) void render_exact(const float2* __restrict__ xs2,
                                                    const float4* __restrict__ packed2,
                                                    const float4* __restrict__ colors,
                                                    const int* __restrict__ etab,
                                                    const unsigned short* __restrict__ subtab,
                                                    const float* __restrict__ bg,
                                                    const int* __restrict__ flags,
                                                    const int* __restrict__ slist,
                                                    float* __restrict__ out, int n) {
    int count = flags[2];
    if (count > n) count = n;
    bool fast = (flags[0] == 0);
    float bgr = bg[0], bgg = bg[1], bgb = bg[2];
    for (int k = blockIdx.x * 256 + threadIdx.x; k < count; k += gridDim.x * 256) {
        int i = slist[k];
        float2 pp = xs2[i];
        float px = pp.x, py = pp.y;
        int ix = (int)__fmul_rn(px, (float)GRIDN); ix = min(max(ix, 0), GRIDN - 1);
        int iy = (int)__fmul_rn(py, (float)GRIDN); iy = min(max(iy, 0), GRIDN - 1);
        int sx = (int)__fmul_rn(px, 256.0f) - ix * 4; sx = min(max(sx, 0), 3);
        int sy = (int)__fmul_rn(py, 256.0f) - iy * 4; sy = min(max(sy, 0), 3);
        const unsigned short* sr = subtab + (size_t)((ix * 4 + sx) * 256 + (iy * 4 + sy)) * 16;
        int cnt = sr[0];
        float cr = bgr, cg = bgg, cb = bgb;
        int win = -1;
        if (cnt != (int)SENTV) {
            for (int s = 0; s < cnt; ++s)
                test_g((int)sr[1 + s], px, py, fast, win, cr, cg, cb, packed2, colors);
        } else {
            const int* prow = etab + (size_t)(ix * GRIDN + iy) * EROW;
            int pc = prow[0];
            for (int s = 0; s < pc; ++s)
                test_g(prow[1 + s], px, py, fast, win, cr, cg, cb, packed2, colors);
        }
        if (fast && win >= 0) {
            float4 C = colors[win];
            cr = C.x; cg = C.y; cb = C.z;
        }
        float* ob = out + (size_t)i * 3;
        ob[0] = cr; ob[1] = cg; ob[2] = cb;
    }
}

// ---------------------------------------------------------------------------
// Fallback render (parent lists, LDS-staged) if ws_size too small.
// ---------------------------------------------------------------------------
__global__ __launch_bounds__(1024) void render_fb(const float2* __restrict__ xs,
                                                  const float4* __restrict__ packed2,
                                                  const float4* __restrict__ colors,
                                                  const int* __restrict__ etab,
                                                  const float* __restrict__ bg,
                                                  float* __restrict__ out, int n, int nprim) {
    __shared__ float4 sA[MAXPRIM];
    __shared__ float4 sBsk[MAXPRIM + 4];
    __shared__ int sflag;
    if (threadIdx.x == 0) sflag = 0;
    __syncthreads();

    int i = blockIdx.x * 1024 + threadIdx.x;
    bool valid = i < n;
    float px = 0.0f, py = 0.0f;
    int row = 0;
    int4 c0 = make_int4(0, 0, 0, 0), c1 = make_int4(0, 0, 0, 0);
    if (valid) {
        float2 pxy = xs[i];
        px = pxy.x; py = pxy.y;
        int ix = (int)__fmul_rn(px, (float)GRIDN);
        ix = min(max(ix, 0), GRIDN - 1);
        int iy = (int)__fmul_rn(py, (float)GRIDN);
        iy = min(max(iy, 0), GRIDN - 1);
        row = (ix * GRIDN + iy) * EROW;
        c0 = *(const int4*)(etab + row);
        c1 = *(const int4*)(etab + row + 4);
    }
    for (int t = threadIdx.x; t < nprim; t += 1024) {
        sA[t] = packed2[t * 2 + 0];
        sBsk[t + 4] = packed2[t * 2 + 1];
        if (colors[t].w != 1.0f) sflag = 1;
    }
    __syncthreads();
    int cnt = valid ? c0.x : 0;
    float cr = bg[0], cg = bg[1], cb = bg[2];
    int win = -1;
    bool fast = (sflag == 0);
#define TESTL(e)                                                               \
    {                                                                          \
        float4 A = sA[e];                                                      \
        float4 Bv = sBsk[(e) + 4];                                             \
        CORE_EVAL(A, Bv);                                                      \
        if (fast) {                                                            \
            if (s2 <= Bv.x) win = (e);                                         \
        } else {                                                               \
            float4 C = colors[e];                                              \
            float a = (s2 <= Bv.x) ? C.w : 0.0f;                               \
            float om = __fsub_rn(1.0f, a);                                     \
            cr = __fadd_rn(__fmul_rn(cr, om), __fmul_rn(C.x, a));              \
            cg = __fadd_rn(__fmul_rn(cg, om), __fmul_rn(C.y, a));              \
            cb = __fadd_rn(__fmul_rn(cb, om), __fmul_rn(C.z, a));              \
        }                                                                      \
    }
    if (cnt > 0) TESTL(c0.y);
    if (cnt > 1) TESTL(c0.z);
    if (cnt > 2) TESTL(c0.w);
    if (cnt > 3) TESTL(c1.x);
    if (cnt > 4) TESTL(c1.y);
    if (cnt > 5) TESTL(c1.z);
    if (cnt > 6) TESTL(c1.w);
    for (int base = 7; base < cnt; base += 4) {
        int4 c = *(const int4*)(etab + row + 1 + base);
        if (base + 0 < cnt) TESTL(c.x);
        if (base + 1 < cnt) TESTL(c.y);
        if (base + 2 < cnt) TESTL(c.z);
        if (base + 3 < cnt) TESTL(c.w);
    }
#undef TESTL
    if (valid) {
        if (fast && win >= 0) {
            float4 C = colors[win];
            cr = C.x; cg = C.y; cb = C.z;
        }
        out[(size_t)i * 3 + 0] = cr;
        out[(size_t)i * 3 + 1] = cg;
        out[(size_t)i * 3 + 2] = cb;
    }
}

extern "C" void kernel_launch(void* const* d_in, const int* in_sizes, int n_in,
                              void* d_out, int out_size, void* d_ws, size_t ws_size,
                              hipStream_t stream) {
    const float* x  = (const float*)d_in[0];
    const float* cp = (const float*)d_in[1];
    const float* sw = (const float*)d_in[2];
    const float* fc = (const float*)d_in[3];
    const float* op = (const float*)d_in[4];
    const float* bg = (const float*)d_in[5];
    float* out = (float*)d_out;

    int npts  = in_sizes[0] / 2;
    int nprim = in_sizes[2];

    char* ws = (char*)d_ws;
    float4* packed2 = (float4*)(ws + WS_PACKED2);
    float4* colors  = (float4*)(ws + WS_COLORS);
    int* etab       = (int*)(ws + WS_ETAB);
    int* flags      = (int*)(ws + WS_FLAGS);
    unsigned short* subtab = (unsigned short*)(ws + WS_SUBTAB);
    unsigned short* lut    = (unsigned short*)(ws + WS_LUT);
    int* slist      = (int*)(ws + WS_LIST);

    size_t need = (size_t)WS_LIST + (size_t)npts * 4u;
    bool use_lut = (ws_size >= need);

    hipMemsetAsync(flags, 0, 16, stream);
    if (use_lut) {
        prep2<<<GRIDN * GRIDN / 16, 1024, 0, stream>>>(cp, sw, fc, op, packed2, colors,
                                                       etab, flags, subtab, nprim, 1);
        classify<<<(LUTN * LUTN) / 256, 256, 0, stream>>>(packed2, subtab, flags, lut);
        int nblk = (npts + 1023) / 1024;
        render_fast<<<nblk, 512, 0, stream>>>((const float4*)x, colors, lut, bg,
                                              flags, slist, out, npts);
        render_exact<<<1024, 256, 0, stream>>>((const float2*)x, packed2, colors,
                                               etab, subtab, bg, flags, slist, out, npts);
    } else {
        prep2<<<GRIDN * GRIDN / 16, 1024, 0, stream>>>(cp, sw, fc, op, packed2, colors,
                                                       etab, flags, subtab, nprim, 0);
        render_fb<<<(npts + 1023) / 1024, 1024, 0, stream>>>((const float2*)x, packed2,
                                                             colors, etab, bg, out,
                                                             npts, nprim);
    }
}

// Round 13
// 99.897 us; speedup vs baseline: 4.5269x; 4.5269x over previous
//
#include <hip/hip_runtime.h>
#include <math.h>

#define GRIDN 64
#define MAXE 32
#define MAXPRIM 1024
#define EROW 36        // parent row: [cnt, e0..e31, pad x3]
#define SCAP2 15
#define SENTV 0xFFFF
#define LUTN 1024

// workspace layout (bytes)
#define WS_PACKED2   0u            // 1024*32
#define WS_COLORS    32768u        // 1024*16
#define WS_ETAB      49152u        // 4096*36*4 -> ends 638976
#define WS_FLAGS     638976u       // ints: [0] opac!=1, [1] parent-trunc
#define WS_SUBTAB    655360u       // 65536*32 = 2 MB -> ends 2752512
#define WS_LUT       2752512u      // 1024*1024*2 = 2 MB -> ends 4849664
#define WS_BCOUNT    4849664u      // nblk*4 (<= 16 KB) -> ends 4866048
#define WS_LIST      4866048u      // nblk*1024*4 ~= npts*4

// exact core: t = rn(td/denom) (double-recip mul), s2 <= Tf <=> rn(sqrt(s2)) <= w
#define CORE_EVAL(A, Bv)                                                         \
    float relx = __fsub_rn(px, A.x);                                             \
    float rely = __fsub_rn(py, A.y);                                             \
    float td = __fadd_rn(__fmul_rn(relx, A.z), __fmul_rn(rely, A.w));            \
    double inv = __hiloint2double(__float_as_int(Bv.z), __float_as_int(Bv.y));   \
    float tt = (float)((double)td * inv);                                        \
    tt = fminf(fmaxf(tt, 0.0f), 1.0f);                                           \
    float qx = __fsub_rn(relx, __fmul_rn(tt, A.z));                              \
    float qy = __fsub_rn(rely, __fmul_rn(tt, A.w));                              \
    float s2 = __fadd_rn(__fmul_rn(qx, qx), __fmul_rn(qy, qy));

// ---------------------------------------------------------------------------
// Kernel 1 (fused): parent grid build + subgrid prune + (block 0) prim pack.
// ---------------------------------------------------------------------------
__global__ __launch_bounds__(1024) void prep2(const float* __restrict__ cp,
                                              const float* __restrict__ sw,
                                              const float* __restrict__ fc,
                                              const float* __restrict__ op,
                                              float4* __restrict__ packed2,
                                              float4* __restrict__ colors,
                                              int* __restrict__ etab,
                                              int* __restrict__ flags,
                                              unsigned short* __restrict__ subtab,
                                              int nprim, int do_sub) {
    __shared__ float4 saabb[MAXPRIM];
    __shared__ float4 sseg[MAXPRIM];
    __shared__ float  sww[MAXPRIM];
    __shared__ int    srows[16][EROW];
    int tid = threadIdx.x;
    for (int p = tid; p < nprim; p += 1024) {
        float x0 = cp[p * 6 + 0], y0 = cp[p * 6 + 1];
        float x1 = cp[p * 6 + 2], y1 = cp[p * 6 + 3];
        float w = sw[p];
        saabb[p] = make_float4(__fsub_rn(fminf(x0, x1), w), __fadd_rn(fmaxf(x0, x1), w),
                               __fsub_rn(fminf(y0, y1), w), __fadd_rn(fmaxf(y0, y1), w));
        sseg[p] = make_float4(x0, y0, __fsub_rn(x1, x0), __fsub_rn(y1, y0));
        sww[p] = w;
    }
    __syncthreads();

    int wid = tid >> 6, lane = tid & 63;
    int cell = blockIdx.x * 16 + wid;
    {
        int ixc = cell >> 6, iyc = cell & 63;
        float lox = (float)ixc * (1.0f / GRIDN);
        float hix = (float)(ixc + 1) * (1.0f / GRIDN);
        float loy = (float)iyc * (1.0f / GRIDN);
        float hiy = (float)(iyc + 1) * (1.0f / GRIDN);
        int total = 0;
        int* row = etab + (size_t)cell * EROW;
        for (int base = 0; base < nprim; base += 64) {
            int p = base + lane;
            bool ov = false;
            if (p < nprim) {
                float4 bb = saabb[p];
                ov = (bb.x < hix) && (bb.y >= lox) && (bb.z < hiy) && (bb.w >= loy);
            }
            unsigned long long m = __ballot(ov);
            if (ov) {
                int pos = total + (int)__popcll(m & ((1ull << lane) - 1ull));
                if (pos < MAXE) { row[1 + pos] = p; srows[wid][1 + pos] = p; }
            }
            total += (int)__popcll(m);
        }
        if (lane == 0) {
            int c = total < MAXE ? total : MAXE;
            row[0] = c;
            srows[wid][0] = c;
            if (total > MAXE) atomicOr(&flags[1], 1);
        }
    }
    __syncthreads();

    if (do_sub && tid < 256) {
        int lp = tid >> 4;
        int sub = tid & 15;
        int pcell = blockIdx.x * 16 + lp;
        int ix = pcell >> 6, iy = pcell & 63;
        int gx = ix * 4 + (sub >> 2), gy = iy * 4 + (sub & 3);
        double clx = (double)gx * (1.0 / 256.0);
        double chx = (double)(gx + 1) * (1.0 / 256.0);
        double cly = (double)gy * (1.0 / 256.0);
        double chy = (double)(gy + 1) * (1.0 / 256.0);
        int cnt = srows[lp][0];
        unsigned short* srow = subtab + (size_t)(gx * 256 + gy) * 16;
        int oc = 0;
        for (int s = 0; s < cnt; ++s) {
            int e = srows[lp][1 + s];
            float4 A = sseg[e];
            double W = (double)sww[e] + 1e-5;
            double lx = clx - W, hx = chx + W, ly = cly - W, hy = chy + W;
            double ax = (double)A.x, ay = (double)A.y;
            double dx = (double)A.z, dy = (double)A.w;
            double t0 = 0.0, t1 = 1.0;
            bool ok = true;
            if (fabs(dx) > 1e-300) {
                double ta = (lx - ax) / dx, tb = (hx - ax) / dx;
                t0 = fmax(t0, fmin(ta, tb));
                t1 = fmin(t1, fmax(ta, tb));
            } else if (ax < lx || ax > hx) ok = false;
            if (ok) {
                if (fabs(dy) > 1e-300) {
                    double ta = (ly - ay) / dy, tb = (hy - ay) / dy;
                    t0 = fmax(t0, fmin(ta, tb));
                    t1 = fmin(t1, fmax(ta, tb));
                } else if (ay < ly || ay > hy) ok = false;
            }
            if (ok && t0 <= t1) {
                if (oc < SCAP2) srow[1 + oc] = (unsigned short)e;
                ++oc;
            }
        }
        int filled = oc < SCAP2 ? oc : SCAP2;
        for (int k = filled; k < SCAP2; ++k) srow[1 + k] = 0;
        srow[0] = (oc <= SCAP2) ? (unsigned short)oc : (unsigned short)SENTV;
    }

    if (blockIdx.x == 0) {
        bool bad = false;
        for (int p = tid; p < nprim; p += 1024) {
            float x0 = cp[p * 6 + 0], y0 = cp[p * 6 + 1];
            float x1 = cp[p * 6 + 2], y1 = cp[p * 6 + 3];
            float w = sw[p];
            float dx = __fsub_rn(x1, x0);
            float dy = __fsub_rn(y1, y0);
            float dd = __fadd_rn(__fmul_rn(dx, dx), __fmul_rn(dy, dy));
            float denom = fmaxf(dd, 1e-12f);
            double inv = 1.0 / (double)denom;
            unsigned wb = __float_as_uint(w);
            bool even = (wb & 1u) == 0u;
            float wn = __uint_as_float(wb + 1u);
            double md = 0.5 * ((double)w + (double)wn);
            double m2 = md * md;
            float Tf = (float)m2;
            if ((double)Tf > m2) Tf = __uint_as_float(__float_as_uint(Tf) - 1u);
            if (!even && (double)Tf == m2) Tf = __uint_as_float(__float_as_uint(Tf) - 1u);
            unsigned long long ib = __double_as_longlong(inv);
            packed2[p * 2 + 0] = make_float4(x0, y0, dx, dy);
            packed2[p * 2 + 1] = make_float4(Tf,
                                             __uint_as_float((unsigned)(ib & 0xffffffffull)),
                                             __uint_as_float((unsigned)(ib >> 32)),
                                             w);
            float opv = op[p];
            colors[p] = make_float4(fc[p * 3 + 0], fc[p * 3 + 1], fc[p * 3 + 2], opv);
            if (opv != 1.0f) bad = true;
        }
        if (bad) atomicOr(&flags[0], 1);
    }
}

// ---------------------------------------------------------------------------
// Kernel 2: classify 1024x1024 pixel LUT (tri-state, conservative f64 margins).
// lut: 0 = background, e+1 = decided winner, 0xFFFF = exact path.
// ---------------------------------------------------------------------------
__global__ __launch_bounds__(256) void classify(const float4* __restrict__ packed2,
                                                const unsigned short* __restrict__ subtab,
                                                const int* __restrict__ flags,
                                                unsigned short* __restrict__ lut) {
    int pi = blockIdx.x * 256 + threadIdx.x;
    int pix = pi >> 10, piy = pi & 1023;
    if ((flags[0] | flags[1]) != 0) { lut[pi] = (unsigned short)SENTV; return; }
    const unsigned short* sr = subtab + (size_t)((pix >> 2) * 256 + (piy >> 2)) * 16;
    int cnt = sr[0];
    if (cnt == (int)SENTV) { lut[pi] = (unsigned short)SENTV; return; }
    double plx = (double)pix * (1.0 / LUTN) - 1e-6;
    double phx = (double)(pix + 1) * (1.0 / LUTN) + 1e-6;
    double ply = (double)piy * (1.0 / LUTN) - 1e-6;
    double phy = (double)(piy + 1) * (1.0 / LUTN) + 1e-6;
    unsigned short ans = 0;
    for (int s = cnt - 1; s >= 0; --s) {
        int e = sr[1 + s];
        float4 A = packed2[e * 2 + 0];
        float4 B = packed2[e * 2 + 1];
        double ax = (double)A.x, ay = (double)A.y;
        double dx = (double)A.z, dy = (double)A.w;
        double w = (double)B.w;
        double W = w + 1e-5;
        double lx = plx - W, hx = phx + W, ly = ply - W, hy = phy + W;
        double t0 = 0.0, t1 = 1.0;
        bool ok = true;
        if (fabs(dx) > 1e-300) {
            double ta = (lx - ax) / dx, tb = (hx - ax) / dx;
            t0 = fmax(t0, fmin(ta, tb));
            t1 = fmin(t1, fmax(ta, tb));
        } else if (ax < lx || ax > hx) ok = false;
        if (ok) {
            if (fabs(dy) > 1e-300) {
                double ta = (ly - ay) / dy, tb = (hy - ay) / dy;
                t0 = fmax(t0, fmin(ta, tb));
                t1 = fmin(t1, fmax(ta, tb));
            } else if (ay < ly || ay > hy) ok = false;
        }
        if (!ok || t0 > t1) continue;            // fully outside
        double wm = w - 1e-5;
        bool allin = false;
        if (wm > 0.0) {
            double inv = __hiloint2double(__float_as_int(B.z), __float_as_int(B.y));
            double wm2 = wm * wm;
            allin = true;
#pragma unroll
            for (int c = 0; c < 4; ++c) {
                double cx = (c & 1) ? phx : plx;
                double cy = (c & 2) ? phy : ply;
                double rx = cx - ax, ry = cy - ay;
                double t = (rx * dx + ry * dy) * inv;
                t = fmin(fmax(t, 0.0), 1.0);
                double qx = rx - t * dx, qy = ry - t * dy;
                if (qx * qx + qy * qy > wm2) { allin = false; break; }
            }
        }
        ans = allin ? (unsigned short)(e + 1) : (unsigned short)SENTV;
        break;
    }
    lut[pi] = ans;
}

// ---------------------------------------------------------------------------
// Kernel 3: fast render. Per point: 1 LUT gather -> color. Sentinels get bg
// (overwritten by render_exact) so all stores are dense float2s. Sentinel
// indices compacted into the block's PRIVATE slist segment — no atomics.
// ---------------------------------------------------------------------------
__global__ __launch_bounds__(512) void render_fast(const float4* __restrict__ xs4,
                                                   const float4* __restrict__ colors,
                                                   const unsigned short* __restrict__ lut,
                                                   const float* __restrict__ bg,
                                                   int* __restrict__ bcount,
                                                   int* __restrict__ slist,
                                                   float* __restrict__ out, int n) {
    __shared__ int swc[8];
    __shared__ int soff[8];
    int tid = threadIdx.x;
    int wid = tid >> 6, lane = tid & 63;
    long long g0 = (long long)blockIdx.x * 1024 + (long long)tid * 2;
    bool v0 = g0 < (long long)n, v1 = (g0 + 1) < (long long)n;

    float4 P = make_float4(0.f, 0.f, 0.f, 0.f);
    if (v1) {
        P = xs4[g0 >> 1];
    } else if (v0) {
        float2 t2 = ((const float2*)xs4)[g0];
        P.x = t2.x; P.y = t2.y;
    }
    int w0 = 0, w1 = 0;
    if (v0) {
        int ipx = (int)__fmul_rn(P.x, (float)LUTN); ipx = min(max(ipx, 0), LUTN - 1);
        int ipy = (int)__fmul_rn(P.y, (float)LUTN); ipy = min(max(ipy, 0), LUTN - 1);
        w0 = lut[ipx * LUTN + ipy];
    }
    if (v1) {
        int ipx = (int)__fmul_rn(P.z, (float)LUTN); ipx = min(max(ipx, 0), LUTN - 1);
        int ipy = (int)__fmul_rn(P.w, (float)LUTN); ipy = min(max(ipy, 0), LUTN - 1);
        w1 = lut[ipx * LUTN + ipy];
    }
    bool s0 = v0 && (w0 == (int)SENTV);
    bool s1 = v1 && (w1 == (int)SENTV);

    float bgr = bg[0], bgg = bg[1], bgb = bg[2];
    float cr0 = bgr, cg0 = bgg, cb0 = bgb;
    float cr1 = bgr, cg1 = bgg, cb1 = bgb;
    if (!s0 && w0 > 0) { float4 C = colors[w0 - 1]; cr0 = C.x; cg0 = C.y; cb0 = C.z; }
    if (!s1 && w1 > 0) { float4 C = colors[w1 - 1]; cr1 = C.x; cg1 = C.y; cb1 = C.z; }

    float* ob = out + g0 * 3;
    if (v1) {
        *(float2*)(ob + 0) = make_float2(cr0, cg0);
        *(float2*)(ob + 2) = make_float2(cb0, cr1);
        *(float2*)(ob + 4) = make_float2(cg1, cb1);
    } else if (v0) {
        ob[0] = cr0; ob[1] = cg0; ob[2] = cb0;
    }

    // block-private compaction (no global atomics)
    unsigned long long m0 = __ballot(s0);
    unsigned long long m1 = __ballot(s1);
    int c0 = (int)__popcll(m0);
    int wtot = c0 + (int)__popcll(m1);
    if (lane == 0) swc[wid] = wtot;
    __syncthreads();
    if (tid == 0) {
        int s = 0;
        for (int w = 0; w < 8; ++w) { soff[w] = s; s += swc[w]; }
        bcount[blockIdx.x] = s;
    }
    __syncthreads();
    int base = blockIdx.x * 1024 + soff[wid];
    unsigned long long lm = (1ull << lane) - 1ull;
    if (s0) slist[base + (int)__popcll(m0 & lm)] = (int)g0;
    if (s1) slist[base + c0 + (int)__popcll(m1 & lm)] = (int)(g0 + 1);
}

// exact per-prim test, global tables
__device__ __forceinline__ void test_g(int e, float px, float py, bool fast,
                                       int& win, float& cr, float& cg, float& cb,
                                       const float4* __restrict__ packed2,
                                       const float4* __restrict__ colors) {
    float4 A = packed2[e * 2 + 0];
    float4 Bv = packed2[e * 2 + 1];
    CORE_EVAL(A, Bv);
    if (fast) {
        if (s2 <= Bv.x) win = e;
    } else {
        float4 C = colors[e];
        float a = (s2 <= Bv.x) ? C.w : 0.0f;
        float om = __fsub_rn(1.0f, a);
        cr = __fadd_rn(__fmul_rn(cr, om), __fmul_rn(C.x, a));
        cg = __fadd_rn(__fmul_rn(cg, om), __fmul_rn(C.y, a));
        cb = __fadd_rn(__fmul_rn(cb, om), __fmul_rn(C.z, a));
    }
}

// ---------------------------------------------------------------------------
// Kernel 4: exact render — one block per render_fast segment, dense lanes.
// ---------------------------------------------------------------------------
__global__ __launch_bounds__(256) void render_exact(const float2* __restrict__ xs2,
                                                    const float4* __restrict__ packed2,
                                                    const float4* __restrict__ colors,
                                                    const int* __restrict__ etab,
                                                    const unsigned short* __restrict__ subtab,
                                                    const float* __restrict__ bg,
                                                    const int* __restrict__ flags,
                                                    const int* __restrict__ bcount,
                                                    const int* __restrict__ slist,
                                                    float* __restrict__ out) {
    int seg = blockIdx.x;
    int count = bcount[seg];
    if (count == 0) return;
    bool fast = (flags[0] == 0);
    float bgr = bg[0], bgg = bg[1], bgb = bg[2];
    const int* sl = slist + (size_t)seg * 1024;
    for (int k = threadIdx.x; k < count; k += 256) {
        int i = sl[k];
        float2 pp = xs2[i];
        float px = pp.x, py = pp.y;
        int ix = (int)__fmul_rn(px, (float)GRIDN); ix = min(max(ix, 0), GRIDN - 1);
        int iy = (int)__fmul_rn(py, (float)GRIDN); iy = min(max(iy, 0), GRIDN - 1);
        int sx = (int)__fmul_rn(px, 256.0f) - ix * 4; sx = min(max(sx, 0), 3);
        int sy = (int)__fmul_rn(py, 256.0f) - iy * 4; sy = min(max(sy, 0), 3);
        const unsigned short* sr = subtab + (size_t)((ix * 4 + sx) * 256 + (iy * 4 + sy)) * 16;
        int cnt = sr[0];
        float cr = bgr, cg = bgg, cb = bgb;
        int win = -1;
        if (cnt != (int)SENTV) {
            for (int s = 0; s < cnt; ++s)
                test_g((int)sr[1 + s], px, py, fast, win, cr, cg, cb, packed2, colors);
        } else {
            const int* prow = etab + (size_t)(ix * GRIDN + iy) * EROW;
            int pc = prow[0];
            for (int s = 0; s < pc; ++s)
                test_g(prow[1 + s], px, py, fast, win, cr, cg, cb, packed2, colors);
        }
        if (fast && win >= 0) {
            float4 C = colors[win];
            cr = C.x; cg = C.y; cb = C.z;
        }
        float* ob = out + (size_t)i * 3;
        ob[0] = cr; ob[1] = cg; ob[2] = cb;
    }
}

// ---------------------------------------------------------------------------
// Fallback render (parent lists, LDS-staged) if ws_size too small.
// ---------------------------------------------------------------------------
__global__ __launch_bounds__(1024) void render_fb(const float2* __restrict__ xs,
                                                  const float4* __restrict__ packed2,
                                                  const float4* __restrict__ colors,
                                                  const int* __restrict__ etab,
                                                  const float* __restrict__ bg,
                                                  float* __restrict__ out, int n, int nprim) {
    __shared__ float4 sA[MAXPRIM];
    __shared__ float4 sBsk[MAXPRIM + 4];
    __shared__ int sflag;
    if (threadIdx.x == 0) sflag = 0;
    __syncthreads();

    int i = blockIdx.x * 1024 + threadIdx.x;
    bool valid = i < n;
    float px = 0.0f, py = 0.0f;
    int row = 0;
    int4 c0 = make_int4(0, 0, 0, 0), c1 = make_int4(0, 0, 0, 0);
    if (valid) {
        float2 pxy = xs[i];
        px = pxy.x; py = pxy.y;
        int ix = (int)__fmul_rn(px, (float)GRIDN);
        ix = min(max(ix, 0), GRIDN - 1);
        int iy = (int)__fmul_rn(py, (float)GRIDN);
        iy = min(max(iy, 0), GRIDN - 1);
        row = (ix * GRIDN + iy) * EROW;
        c0 = *(const int4*)(etab + row);
        c1 = *(const int4*)(etab + row + 4);
    }
    for (int t = threadIdx.x; t < nprim; t += 1024) {
        sA[t] = packed2[t * 2 + 0];
        sBsk[t + 4] = packed2[t * 2 + 1];
        if (colors[t].w != 1.0f) sflag = 1;
    }
    __syncthreads();
    int cnt = valid ? c0.x : 0;
    float cr = bg[0], cg = bg[1], cb = bg[2];
    int win = -1;
    bool fast = (sflag == 0);
#define TESTL(e)                                                               \
    {                                                                          \
        float4 A = sA[e];                                                      \
        float4 Bv = sBsk[(e) + 4];                                             \
        CORE_EVAL(A, Bv);                                                      \
        if (fast) {                                                            \
            if (s2 <= Bv.x) win = (e);                                         \
        } else {                                                               \
            float4 C = colors[e];                                              \
            float a = (s2 <= Bv.x) ? C.w : 0.0f;                               \
            float om = __fsub_rn(1.0f, a);                                     \
            cr = __fadd_rn(__fmul_rn(cr, om), __fmul_rn(C.x, a));              \
            cg = __fadd_rn(__fmul_rn(cg, om), __fmul_rn(C.y, a));              \
            cb = __fadd_rn(__fmul_rn(cb, om), __fmul_rn(C.z, a));              \
        }                                                                      \
    }
    if (cnt > 0) TESTL(c0.y);
    if (cnt > 1) TESTL(c0.z);
    if (cnt > 2) TESTL(c0.w);
    if (cnt > 3) TESTL(c1.x);
    if (cnt > 4) TESTL(c1.y);
    if (cnt > 5) TESTL(c1.z);
    if (cnt > 6) TESTL(c1.w);
    for (int base = 7; base < cnt; base += 4) {
        int4 c = *(const int4*)(etab + row + 1 + base);
        if (base + 0 < cnt) TESTL(c.x);
        if (base + 1 < cnt) TESTL(c.y);
        if (base + 2 < cnt) TESTL(c.z);
        if (base + 3 < cnt) TESTL(c.w);
    }
#undef TESTL
    if (valid) {
        if (fast && win >= 0) {
            float4 C = colors[win];
            cr = C.x; cg = C.y; cb = C.z;
        }
        out[(size_t)i * 3 + 0] = cr;
        out[(size_t)i * 3 + 1] = cg;
        out[(size_t)i * 3 + 2] = cb;
    }
}

extern "C" void kernel_launch(void* const* d_in, const int* in_sizes, int n_in,
                              void* d_out, int out_size, void* d_ws, size_t ws_size,
                              hipStream_t stream) {
    const float* x  = (const float*)d_in[0];
    const float* cp = (const float*)d_in[1];
    const float* sw = (const float*)d_in[2];
    const float* fc = (const float*)d_in[3];
    const float* op = (const float*)d_in[4];
    const float* bg = (const float*)d_in[5];
    float* out = (float*)d_out;

    int npts  = in_sizes[0] / 2;
    int nprim = in_sizes[2];
    int nblk  = (npts + 1023) / 1024;

    char* ws = (char*)d_ws;
    float4* packed2 = (float4*)(ws + WS_PACKED2);
    float4* colors  = (float4*)(ws + WS_COLORS);
    int* etab       = (int*)(ws + WS_ETAB);
    int* flags      = (int*)(ws + WS_FLAGS);
    unsigned short* subtab = (unsigned short*)(ws + WS_SUBTAB);
    unsigned short* lut    = (unsigned short*)(ws + WS_LUT);
    int* bcount     = (int*)(ws + WS_BCOUNT);
    int* slist      = (int*)(ws + WS_LIST);

    size_t need = (size_t)WS_LIST + (size_t)nblk * 1024u * 4u;
    bool use_lut = (ws_size >= need);

    hipMemsetAsync(flags, 0, 16, stream);
    if (use_lut) {
        prep2<<<GRIDN * GRIDN / 16, 1024, 0, stream>>>(cp, sw, fc, op, packed2, colors,
                                                       etab, flags, subtab, nprim, 1);
        classify<<<(LUTN * LUTN) / 256, 256, 0, stream>>>(packed2, subtab, flags, lut);
        render_fast<<<nblk, 512, 0, stream>>>((const float4*)x, colors, lut, bg,
                                              bcount, slist, out, npts);
        render_exact<<<nblk, 256, 0, stream>>>((const float2*)x, packed2, colors,
                                               etab, subtab, bg, flags, bcount, slist, out);
    } else {
        prep2<<<GRIDN * GRIDN / 16, 1024, 0, stream>>>(cp, sw, fc, op, packed2, colors,
                                                       etab, flags, subtab, nprim, 0);
        render_fb<<<(npts + 1023) / 1024, 1024, 0, stream>>>((const float2*)x, packed2,
                                                             colors, etab, bg, out,
                                                             npts, nprim);
    }
}

// Round 14
// 99.030 us; speedup vs baseline: 4.5666x; 1.0088x over previous
//
#include <hip/hip_runtime.h>
#include <math.h>

#define GRIDN 64
#define MAXE 32
#define MAXPRIM 1024
#define EROW 36
#define SCAP2 15
#define SENTV 0xFFFF
#define LUTN 1024

// workspace layout (bytes)
#define WS_PACKED2   0u
#define WS_COLORS    32768u
#define WS_ETAB      49152u        // ends 638976
#define WS_FLAGS     638976u
#define WS_SUBTAB    655360u       // ends 2752512
#define WS_LUT       2752512u      // ends 4849664
#define WS_BCOUNT    4849664u      // 8192*4 -> ends 4882432
#define WS_LIST      4882432u      // nseg*512*4

#define CORE_EVAL(A, Bv)                                                         \
    float relx = __fsub_rn(px, A.x);                                             \
    float rely = __fsub_rn(py, A.y);                                             \
    float td = __fadd_rn(__fmul_rn(relx, A.z), __fmul_rn(rely, A.w));            \
    double inv = __hiloint2double(__float_as_int(Bv.z), __float_as_int(Bv.y));   \
    float tt = (float)((double)td * inv);                                        \
    tt = fminf(fmaxf(tt, 0.0f), 1.0f);                                           \
    float qx = __fsub_rn(relx, __fmul_rn(tt, A.z));                              \
    float qy = __fsub_rn(rely, __fmul_rn(tt, A.w));                              \
    float s2 = __fadd_rn(__fmul_rn(qx, qx), __fmul_rn(qy, qy));

// ---------------------------------------------------------------------------
// Kernel 1 (fused): parent grid build + subgrid prune (f64, exact) + pack.
// ---------------------------------------------------------------------------
__global__ __launch_bounds__(1024) void prep2(const float* __restrict__ cp,
                                              const float* __restrict__ sw,
                                              const float* __restrict__ fc,
                                              const float* __restrict__ op,
                                              float4* __restrict__ packed2,
                                              float4* __restrict__ colors,
                                              int* __restrict__ etab,
                                              int* __restrict__ flags,
                                              unsigned short* __restrict__ subtab,
                                              int nprim, int do_sub) {
    __shared__ float4 saabb[MAXPRIM];
    __shared__ float4 sseg[MAXPRIM];
    __shared__ float  sww[MAXPRIM];
    __shared__ int    srows[16][EROW];
    int tid = threadIdx.x;
    for (int p = tid; p < nprim; p += 1024) {
        float x0 = cp[p * 6 + 0], y0 = cp[p * 6 + 1];
        float x1 = cp[p * 6 + 2], y1 = cp[p * 6 + 3];
        float w = sw[p];
        saabb[p] = make_float4(__fsub_rn(fminf(x0, x1), w), __fadd_rn(fmaxf(x0, x1), w),
                               __fsub_rn(fminf(y0, y1), w), __fadd_rn(fmaxf(y0, y1), w));
        sseg[p] = make_float4(x0, y0, __fsub_rn(x1, x0), __fsub_rn(y1, y0));
        sww[p] = w;
    }
    __syncthreads();

    int wid = tid >> 6, lane = tid & 63;
    int cell = blockIdx.x * 16 + wid;
    {
        int ixc = cell >> 6, iyc = cell & 63;
        float lox = (float)ixc * (1.0f / GRIDN);
        float hix = (float)(ixc + 1) * (1.0f / GRIDN);
        float loy = (float)iyc * (1.0f / GRIDN);
        float hiy = (float)(iyc + 1) * (1.0f / GRIDN);
        int total = 0;
        int* row = etab + (size_t)cell * EROW;
        for (int base = 0; base < nprim; base += 64) {
            int p = base + lane;
            bool ov = false;
            if (p < nprim) {
                float4 bb = saabb[p];
                ov = (bb.x < hix) && (bb.y >= lox) && (bb.z < hiy) && (bb.w >= loy);
            }
            unsigned long long m = __ballot(ov);
            if (ov) {
                int pos = total + (int)__popcll(m & ((1ull << lane) - 1ull));
                if (pos < MAXE) { row[1 + pos] = p; srows[wid][1 + pos] = p; }
            }
            total += (int)__popcll(m);
        }
        if (lane == 0) {
            int c = total < MAXE ? total : MAXE;
            row[0] = c;
            srows[wid][0] = c;
            if (total > MAXE) atomicOr(&flags[1], 1);
        }
    }
    __syncthreads();

    if (do_sub && tid < 256) {
        int lp = tid >> 4;
        int sub = tid & 15;
        int pcell = blockIdx.x * 16 + lp;
        int ix = pcell >> 6, iy = pcell & 63;
        int gx = ix * 4 + (sub >> 2), gy = iy * 4 + (sub & 3);
        double clx = (double)gx * (1.0 / 256.0);
        double chx = (double)(gx + 1) * (1.0 / 256.0);
        double cly = (double)gy * (1.0 / 256.0);
        double chy = (double)(gy + 1) * (1.0 / 256.0);
        int cnt = srows[lp][0];
        unsigned short* srow = subtab + (size_t)(gx * 256 + gy) * 16;
        int oc = 0;
        for (int s = 0; s < cnt; ++s) {
            int e = srows[lp][1 + s];
            float4 A = sseg[e];
            double W = (double)sww[e] + 1e-5;
            double lx = clx - W, hx = chx + W, ly = cly - W, hy = chy + W;
            double ax = (double)A.x, ay = (double)A.y;
            double dx = (double)A.z, dy = (double)A.w;
            double t0 = 0.0, t1 = 1.0;
            bool ok = true;
            if (fabs(dx) > 1e-300) {
                double ta = (lx - ax) / dx, tb = (hx - ax) / dx;
                t0 = fmax(t0, fmin(ta, tb));
                t1 = fmin(t1, fmax(ta, tb));
            } else if (ax < lx || ax > hx) ok = false;
            if (ok) {
                if (fabs(dy) > 1e-300) {
                    double ta = (ly - ay) / dy, tb = (hy - ay) / dy;
                    t0 = fmax(t0, fmin(ta, tb));
                    t1 = fmin(t1, fmax(ta, tb));
                } else if (ay < ly || ay > hy) ok = false;
            }
            if (ok && t0 <= t1) {
                if (oc < SCAP2) srow[1 + oc] = (unsigned short)e;
                ++oc;
            }
        }
        int filled = oc < SCAP2 ? oc : SCAP2;
        for (int k = filled; k < SCAP2; ++k) srow[1 + k] = 0;
        srow[0] = (oc <= SCAP2) ? (unsigned short)oc : (unsigned short)SENTV;
    }

    if (blockIdx.x == 0) {
        bool bad = false;
        for (int p = tid; p < nprim; p += 1024) {
            float x0 = cp[p * 6 + 0], y0 = cp[p * 6 + 1];
            float x1 = cp[p * 6 + 2], y1 = cp[p * 6 + 3];
            float w = sw[p];
            float dx = __fsub_rn(x1, x0);
            float dy = __fsub_rn(y1, y0);
            float dd = __fadd_rn(__fmul_rn(dx, dx), __fmul_rn(dy, dy));
            float denom = fmaxf(dd, 1e-12f);
            double inv = 1.0 / (double)denom;
            unsigned wb = __float_as_uint(w);
            bool even = (wb & 1u) == 0u;
            float wn = __uint_as_float(wb + 1u);
            double md = 0.5 * ((double)w + (double)wn);
            double m2 = md * md;
            float Tf = (float)m2;
            if ((double)Tf > m2) Tf = __uint_as_float(__float_as_uint(Tf) - 1u);
            if (!even && (double)Tf == m2) Tf = __uint_as_float(__float_as_uint(Tf) - 1u);
            unsigned long long ib = __double_as_longlong(inv);
            packed2[p * 2 + 0] = make_float4(x0, y0, dx, dy);
            packed2[p * 2 + 1] = make_float4(Tf,
                                             __uint_as_float((unsigned)(ib & 0xffffffffull)),
                                             __uint_as_float((unsigned)(ib >> 32)),
                                             w);
            float opv = op[p];
            colors[p] = make_float4(fc[p * 3 + 0], fc[p * 3 + 1], fc[p * 3 + 2], opv);
            if (opv != 1.0f) bad = true;
        }
        if (bad) atomicOr(&flags[0], 1);
    }
}

// ---------------------------------------------------------------------------
// Kernel 2: classify LUT — ALL F32 (margins >> f32 error >> ref's fp32 skin).
// outside: capsule(w+3e-5) slab misses pixel rect expanded 1e-5 (conservative
// toward "intersects"). inside: all 4 corners dist<=w-1e-5 (convex => exact
// max-at-corners; any-t eval is a sound upper bound on min-dist).
// ---------------------------------------------------------------------------
__global__ __launch_bounds__(256) void classify(const float4* __restrict__ packed2,
                                                const unsigned short* __restrict__ subtab,
                                                const int* __restrict__ flags,
                                                unsigned short* __restrict__ lut) {
    int pi = blockIdx.x * 256 + threadIdx.x;
    int pix = pi >> 10, piy = pi & 1023;
    if ((flags[0] | flags[1]) != 0) { lut[pi] = (unsigned short)SENTV; return; }
    const unsigned short* sr = subtab + (size_t)((pix >> 2) * 256 + (piy >> 2)) * 16;
    int cnt = sr[0];
    if (cnt == (int)SENTV) { lut[pi] = (unsigned short)SENTV; return; }
    float plx = (float)pix * (1.0f / LUTN) - 1e-5f;
    float phx = (float)(pix + 1) * (1.0f / LUTN) + 1e-5f;
    float ply = (float)piy * (1.0f / LUTN) - 1e-5f;
    float phy = (float)(piy + 1) * (1.0f / LUTN) + 1e-5f;
    unsigned short ans = 0;
    for (int s = cnt - 1; s >= 0; --s) {
        int e = sr[1 + s];
        float4 A = packed2[e * 2 + 0];
        float4 B = packed2[e * 2 + 1];
        float ax = A.x, ay = A.y, dx = A.z, dy = A.w;
        float w = B.w;
        float W = w + 3e-5f;
        float lx = plx - W, hx = phx + W, ly = ply - W, hy = phy + W;
        float t0 = 0.0f, t1 = 1.0f;
        bool ok = true;
        if (fabsf(dx) > 1e-20f) {
            float ta = (lx - ax) / dx, tb = (hx - ax) / dx;
            t0 = fmaxf(t0, fminf(ta, tb));
            t1 = fminf(t1, fmaxf(ta, tb));
        } else if (ax < lx || ax > hx) ok = false;
        if (ok) {
            if (fabsf(dy) > 1e-20f) {
                float ta = (ly - ay) / dy, tb = (hy - ay) / dy;
                t0 = fmaxf(t0, fminf(ta, tb));
                t1 = fminf(t1, fmaxf(ta, tb));
            } else if (ay < ly || ay > hy) ok = false;
        }
        if (!ok || t0 > t1) continue;           // fully outside -> next lower
        float wm = w - 1e-5f;
        bool allin = false;
        if (wm > 0.0f) {
            double invd = __hiloint2double(__float_as_int(B.z), __float_as_int(B.y));
            float invf = (float)invd;
            float wm2 = wm * wm - 1e-8f;
            allin = true;
#pragma unroll
            for (int c = 0; c < 4; ++c) {
                float cx = (c & 1) ? phx : plx;
                float cy = (c & 2) ? phy : ply;
                float rx = cx - ax, ry = cy - ay;
                float t = (rx * dx + ry * dy) * invf;
                t = fminf(fmaxf(t, 0.0f), 1.0f);
                float qx = rx - t * dx, qy = ry - t * dy;
                if (qx * qx + qy * qy > wm2) { allin = false; break; }
            }
        }
        ans = allin ? (unsigned short)(e + 1) : (unsigned short)SENTV;
        break;
    }
    lut[pi] = ans;
}

// ---------------------------------------------------------------------------
// Kernel 3: fast render, 8 points/thread, branch-free full-block path.
// All 8 LUT gathers issued before use; per-wave private slist segments
// (no atomics, no syncthreads).
// ---------------------------------------------------------------------------
__global__ __launch_bounds__(512) void render_fast8(const float4* __restrict__ xs4,
                                                    const float4* __restrict__ colors,
                                                    const unsigned short* __restrict__ lut,
                                                    const float* __restrict__ bg,
                                                    int* __restrict__ bcount,
                                                    int* __restrict__ slist,
                                                    float* __restrict__ out, int n) {
    int tid = threadIdx.x, wid = tid >> 6, lane = tid & 63;
    long long pbase = (long long)blockIdx.x * 4096;
    float bgr = bg[0], bgg = bg[1], bgb = bg[2];
    unsigned long long lm = (1ull << lane) - 1ull;
    int seg = blockIdx.x * 8 + wid;
    int segbase = seg * 512;
    int wbase = 0;

#define LIDX(PX, PY)                                                           \
    ({ int ipx_ = (int)__fmul_rn((PX), (float)LUTN);                           \
       ipx_ = min(max(ipx_, 0), LUTN - 1);                                     \
       int ipy_ = (int)__fmul_rn((PY), (float)LUTN);                           \
       ipy_ = min(max(ipy_, 0), LUTN - 1);                                     \
       ipx_ * LUTN + ipy_; })

    if (pbase + 4096 <= (long long)n) {
        const float4* xb = xs4 + (pbase >> 1);
        float4 P0 = xb[tid];
        float4 P1 = xb[512 + tid];
        float4 P2 = xb[1024 + tid];
        float4 P3 = xb[1536 + tid];
        // all 8 gathers issued back-to-back (independent)
        int w0 = lut[LIDX(P0.x, P0.y)];
        int w1 = lut[LIDX(P0.z, P0.w)];
        int w2 = lut[LIDX(P1.x, P1.y)];
        int w3 = lut[LIDX(P1.z, P1.w)];
        int w4 = lut[LIDX(P2.x, P2.y)];
        int w5 = lut[LIDX(P2.z, P2.w)];
        int w6 = lut[LIDX(P3.x, P3.y)];
        int w7 = lut[LIDX(P3.z, P3.w)];

#define EMITK(K, WA, WB)                                                       \
        {                                                                      \
            float4 CA = colors[min(max(WA, 1), MAXPRIM) - 1];                  \
            float4 CB = colors[min(max(WB, 1), MAXPRIM) - 1];                  \
            bool da = (WA > 0) && (WA != (int)SENTV);                          \
            bool db = (WB > 0) && (WB != (int)SENTV);                          \
            float ra = da ? CA.x : bgr, ga = da ? CA.y : bgg, ba = da ? CA.z : bgb; \
            float rb = db ? CB.x : bgr, gb = db ? CB.y : bgg, bb = db ? CB.z : bgb; \
            float* ob = out + (pbase + (K) * 1024 + (long long)tid * 2) * 3;   \
            *(float2*)(ob + 0) = make_float2(ra, ga);                          \
            *(float2*)(ob + 2) = make_float2(ba, rb);                          \
            *(float2*)(ob + 4) = make_float2(gb, bb);                          \
            bool sa = (WA == (int)SENTV), sb = (WB == (int)SENTV);             \
            unsigned long long ma = __ballot(sa);                              \
            if (sa) slist[segbase + wbase + (int)__popcll(ma & lm)] =          \
                (int)(pbase + (K) * 1024 + tid * 2);                           \
            wbase += (int)__popcll(ma);                                        \
            unsigned long long mb = __ballot(sb);                              \
            if (sb) slist[segbase + wbase + (int)__popcll(mb & lm)] =          \
                (int)(pbase + (K) * 1024 + tid * 2 + 1);                       \
            wbase += (int)__popcll(mb);                                        \
        }
        EMITK(0, w0, w1);
        EMITK(1, w2, w3);
        EMITK(2, w4, w5);
        EMITK(3, w6, w7);
#undef EMITK
    } else {
        const float2* xs2 = (const float2*)xs4;
#pragma unroll
        for (int k = 0; k < 4; ++k) {
#pragma unroll
            for (int h = 0; h < 2; ++h) {
                long long g = pbase + k * 1024 + (long long)tid * 2 + h;
                bool v = g < (long long)n;
                int w = 0;
                float px = 0.f, py = 0.f;
                if (v) {
                    float2 t2 = xs2[g];
                    px = t2.x; py = t2.y;
                    w = lut[LIDX(px, py)];
                }
                bool sv = v && (w == (int)SENTV);
                if (v && !sv) {
                    float cr = bgr, cg = bgg, cb = bgb;
                    if (w > 0) { float4 C = colors[w - 1]; cr = C.x; cg = C.y; cb = C.z; }
                    float* ob = out + g * 3;
                    ob[0] = cr; ob[1] = cg; ob[2] = cb;
                } else if (sv) {
                    float* ob = out + g * 3;
                    ob[0] = bgr; ob[1] = bgg; ob[2] = bgb;
                }
                unsigned long long m = __ballot(sv);
                if (sv) slist[segbase + wbase + (int)__popcll(m & lm)] = (int)g;
                wbase += (int)__popcll(m);
            }
        }
    }
#undef LIDX
    if (lane == 0) bcount[seg] = wbase;
}

__device__ __forceinline__ void test_g(int e, float px, float py, bool fast,
                                       int& win, float& cr, float& cg, float& cb,
                                       const float4* __restrict__ packed2,
                                       const float4* __restrict__ colors) {
    float4 A = packed2[e * 2 + 0];
    float4 Bv = packed2[e * 2 + 1];
    CORE_EVAL(A, Bv);
    if (fast) {
        if (s2 <= Bv.x) win = e;
    } else {
        float4 C = colors[e];
        float a = (s2 <= Bv.x) ? C.w : 0.0f;
        float om = __fsub_rn(1.0f, a);
        cr = __fadd_rn(__fmul_rn(cr, om), __fmul_rn(C.x, a));
        cg = __fadd_rn(__fmul_rn(cg, om), __fmul_rn(C.y, a));
        cb = __fadd_rn(__fmul_rn(cb, om), __fmul_rn(C.z, a));
    }
}

// ---------------------------------------------------------------------------
// Kernel 4: exact render — one 64-thread block per wave segment (count<=512).
// ---------------------------------------------------------------------------
__global__ __launch_bounds__(64) void render_exact(const float2* __restrict__ xs2,
                                                   const float4* __restrict__ packed2,
                                                   const float4* __restrict__ colors,
                                                   const int* __restrict__ etab,
                                                   const unsigned short* __restrict__ subtab,
                                                   const float* __restrict__ bg,
                                                   const int* __restrict__ flags,
                                                   const int* __restrict__ bcount,
                                                   const int* __restrict__ slist,
                                                   float* __restrict__ out) {
    int seg = blockIdx.x;
    int count = bcount[seg];
    if (count == 0) return;
    bool fast = (flags[0] == 0);
    float bgr = bg[0], bgg = bg[1], bgb = bg[2];
    const int* sl = slist + (size_t)seg * 512;
    for (int k = threadIdx.x; k < count; k += 64) {
        int i = sl[k];
        float2 pp = xs2[i];
        float px = pp.x, py = pp.y;
        int ix = (int)__fmul_rn(px, (float)GRIDN); ix = min(max(ix, 0), GRIDN - 1);
        int iy = (int)__fmul_rn(py, (float)GRIDN); iy = min(max(iy, 0), GRIDN - 1);
        int sx = (int)__fmul_rn(px, 256.0f) - ix * 4; sx = min(max(sx, 0), 3);
        int sy = (int)__fmul_rn(py, 256.0f) - iy * 4; sy = min(max(sy, 0), 3);
        const unsigned short* sr = subtab + (size_t)((ix * 4 + sx) * 256 + (iy * 4 + sy)) * 16;
        int cnt = sr[0];
        float cr = bgr, cg = bgg, cb = bgb;
        int win = -1;
        if (cnt != (int)SENTV) {
            for (int s = 0; s < cnt; ++s)
                test_g((int)sr[1 + s], px, py, fast, win, cr, cg, cb, packed2, colors);
        } else {
            const int* prow = etab + (size_t)(ix * GRIDN + iy) * EROW;
            int pc = prow[0];
            for (int s = 0; s < pc; ++s)
                test_g(prow[1 + s], px, py, fast, win, cr, cg, cb, packed2, colors);
        }
        if (fast && win >= 0) {
            float4 C = colors[win];
            cr = C.x; cg = C.y; cb = C.z;
        }
        float* ob = out + (size_t)i * 3;
        ob[0] = cr; ob[1] = cg; ob[2] = cb;
    }
}

// ---------------------------------------------------------------------------
// Fallback render if ws_size too small for the LUT pipeline.
// ---------------------------------------------------------------------------
__global__ __launch_bounds__(1024) void render_fb(const float2* __restrict__ xs,
                                                  const float4* __restrict__ packed2,
                                                  const float4* __restrict__ colors,
                                                  const int* __restrict__ etab,
                                                  const float* __restrict__ bg,
                                                  float* __restrict__ out, int n, int nprim) {
    __shared__ float4 sA[MAXPRIM];
    __shared__ float4 sBsk[MAXPRIM + 4];
    __shared__ int sflag;
    if (threadIdx.x == 0) sflag = 0;
    __syncthreads();

    int i = blockIdx.x * 1024 + threadIdx.x;
    bool valid = i < n;
    float px = 0.0f, py = 0.0f;
    int row = 0;
    int4 c0 = make_int4(0, 0, 0, 0), c1 = make_int4(0, 0, 0, 0);
    if (valid) {
        float2 pxy = xs[i];
        px = pxy.x; py = pxy.y;
        int ix = (int)__fmul_rn(px, (float)GRIDN);
        ix = min(max(ix, 0), GRIDN - 1);
        int iy = (int)__fmul_rn(py, (float)GRIDN);
        iy = min(max(iy, 0), GRIDN - 1);
        row = (ix * GRIDN + iy) * EROW;
        c0 = *(const int4*)(etab + row);
        c1 = *(const int4*)(etab + row + 4);
    }
    for (int t = threadIdx.x; t < nprim; t += 1024) {
        sA[t] = packed2[t * 2 + 0];
        sBsk[t + 4] = packed2[t * 2 + 1];
        if (colors[t].w != 1.0f) sflag = 1;
    }
    __syncthreads();
    int cnt = valid ? c0.x : 0;
    float cr = bg[0], cg = bg[1], cb = bg[2];
    int win = -1;
    bool fast = (sflag == 0);
#define TESTL(e)                                                               \
    {                                                                          \
        float4 A = sA[e];                                                      \
        float4 Bv = sBsk[(e) + 4];                                             \
        CORE_EVAL(A, Bv);                                                      \
        if (fast) {                                                            \
            if (s2 <= Bv.x) win = (e);                                         \
        } else {                                                               \
            float4 C = colors[e];                                              \
            float a = (s2 <= Bv.x) ? C.w : 0.0f;                               \
            float om = __fsub_rn(1.0f, a);                                     \
            cr = __fadd_rn(__fmul_rn(cr, om), __fmul_rn(C.x, a));              \
            cg = __fadd_rn(__fmul_rn(cg, om), __fmul_rn(C.y, a));              \
            cb = __fadd_rn(__fmul_rn(cb, om), __fmul_rn(C.z, a));              \
        }                                                                      \
    }
    if (cnt > 0) TESTL(c0.y);
    if (cnt > 1) TESTL(c0.z);
    if (cnt > 2) TESTL(c0.w);
    if (cnt > 3) TESTL(c1.x);
    if (cnt > 4) TESTL(c1.y);
    if (cnt > 5) TESTL(c1.z);
    if (cnt > 6) TESTL(c1.w);
    for (int base = 7; base < cnt; base += 4) {
        int4 c = *(const int4*)(etab + row + 1 + base);
        if (base + 0 < cnt) TESTL(c.x);
        if (base + 1 < cnt) TESTL(c.y);
        if (base + 2 < cnt) TESTL(c.z);
        if (base + 3 < cnt) TESTL(c.w);
    }
#undef TESTL
    if (valid) {
        if (fast && win >= 0) {
            float4 C = colors[win];
            cr = C.x; cg = C.y; cb = C.z;
        }
        out[(size_t)i * 3 + 0] = cr;
        out[(size_t)i * 3 + 1] = cg;
        out[(size_t)i * 3 + 2] = cb;
    }
}

extern "C" void kernel_launch(void* const* d_in, const int* in_sizes, int n_in,
                              void* d_out, int out_size, void* d_ws, size_t ws_size,
                              hipStream_t stream) {
    const float* x  = (const float*)d_in[0];
    const float* cp = (const float*)d_in[1];
    const float* sw = (const float*)d_in[2];
    const float* fc = (const float*)d_in[3];
    const float* op = (const float*)d_in[4];
    const float* bg = (const float*)d_in[5];
    float* out = (float*)d_out;

    int npts  = in_sizes[0] / 2;
    int nprim = in_sizes[2];
    int nblk  = (npts + 4095) / 4096;
    int nseg  = nblk * 8;

    char* ws = (char*)d_ws;
    float4* packed2 = (float4*)(ws + WS_PACKED2);
    float4* colors  = (float4*)(ws + WS_COLORS);
    int* etab       = (int*)(ws + WS_ETAB);
    int* flags      = (int*)(ws + WS_FLAGS);
    unsigned short* subtab = (unsigned short*)(ws + WS_SUBTAB);
    unsigned short* lut    = (unsigned short*)(ws + WS_LUT);
    int* bcount     = (int*)(ws + WS_BCOUNT);
    int* slist      = (int*)(ws + WS_LIST);

    size_t need = (size_t)WS_LIST + (size_t)nseg * 512u * 4u;
    bool use_lut = (ws_size >= need) && (nseg <= 8192);

    hipMemsetAsync(flags, 0, 16, stream);
    if (use_lut) {
        prep2<<<GRIDN * GRIDN / 16, 1024, 0, stream>>>(cp, sw, fc, op, packed2, colors,
                                                       etab, flags, subtab, nprim, 1);
        classify<<<(LUTN * LUTN) / 256, 256, 0, stream>>>(packed2, subtab, flags, lut);
        render_fast8<<<nblk, 512, 0, stream>>>((const float4*)x, colors, lut, bg,
                                               bcount, slist, out, npts);
        render_exact<<<nseg, 64, 0, stream>>>((const float2*)x, packed2, colors,
                                              etab, subtab, bg, flags, bcount, slist, out);
    } else {
        prep2<<<GRIDN * GRIDN / 16, 1024, 0, stream>>>(cp, sw, fc, op, packed2, colors,
                                                       etab, flags, subtab, nprim, 0);
        render_fb<<<(npts + 1023) / 1024, 1024, 0, stream>>>((const float2*)x, packed2,
                                                             colors, etab, bg, out,
                                                             npts, nprim);
    }
}

// Round 15
// 55.828 us; speedup vs baseline: 8.1004x; 1.7739x over previous
//
#include <hip/hip_runtime.h>
#include <math.h>

#define GRIDN 64
#define MAXE 32
#define MAXPRIM 1024
#define EROW 36        // parent row: [cnt, e0..e31, pad x3]
#define SCAP2 15
#define SENTV 0xFFFF

typedef float f32x4 __attribute__((ext_vector_type(4)));
typedef int   i32x4 __attribute__((ext_vector_type(4)));

// workspace layout (bytes)
#define WS_PACKED2   0u            // 1024*32
#define WS_COLORS    32768u        // 1024*16
#define WS_ETAB      49152u        // 4096*36*4 -> ends 638976
#define WS_FLAG      638976u       // 4 B: nonzero if any opacity != 1
#define WS_SUBTAB    655360u       // 65536*32 = 2 MB -> ends 2752512

// exact core: t = rn(td/denom) (double-recip mul), s2 <= Tf <=> rn(sqrt(s2)) <= w
#define CORE_EVAL(A, Bv)                                                         \
    float relx = __fsub_rn(px, (A).x);                                           \
    float rely = __fsub_rn(py, (A).y);                                           \
    float td = __fadd_rn(__fmul_rn(relx, (A).z), __fmul_rn(rely, (A).w));        \
    double inv = __hiloint2double(__float_as_int((Bv).z), __float_as_int((Bv).y)); \
    float tt = (float)((double)td * inv);                                        \
    tt = fminf(fmaxf(tt, 0.0f), 1.0f);                                           \
    float qx = __fsub_rn(relx, __fmul_rn(tt, (A).z));                            \
    float qy = __fsub_rn(rely, __fmul_rn(tt, (A).w));                            \
    float s2 = __fadd_rn(__fmul_rn(qx, qx), __fmul_rn(qy, qy));

// ---------------------------------------------------------------------------
// Kernel 1 (fused): parent grid build + subgrid prune + (block 0) prim pack.
// Block 0 writes flagp[0] directly (no memset/atomics needed).
// ---------------------------------------------------------------------------
__global__ __launch_bounds__(1024) void prep2(const float* __restrict__ cp,
                                              const float* __restrict__ sw,
                                              const float* __restrict__ fc,
                                              const float* __restrict__ op,
                                              float4* __restrict__ packed2,
                                              float4* __restrict__ colors,
                                              int* __restrict__ etab,
                                              int* __restrict__ flagp,
                                              unsigned short* __restrict__ subtab,
                                              int nprim) {
    __shared__ float4 saabb[MAXPRIM];
    __shared__ float4 sseg[MAXPRIM];   // (x0, y0, dx, dy)
    __shared__ float  sww[MAXPRIM];
    __shared__ int    srows[16][EROW];
    __shared__ int    sbad;
    int tid = threadIdx.x;
    if (tid == 0) sbad = 0;
    for (int p = tid; p < nprim; p += 1024) {
        float x0 = cp[p * 6 + 0], y0 = cp[p * 6 + 1];
        float x1 = cp[p * 6 + 2], y1 = cp[p * 6 + 3];
        float w = sw[p];
        saabb[p] = make_float4(__fsub_rn(fminf(x0, x1), w), __fadd_rn(fmaxf(x0, x1), w),
                               __fsub_rn(fminf(y0, y1), w), __fadd_rn(fmaxf(y0, y1), w));
        sseg[p] = make_float4(x0, y0, __fsub_rn(x1, x0), __fsub_rn(y1, y0));
        sww[p] = w;
    }
    __syncthreads();

    // ---- phase B: parent rows (one wave per parent cell) ----
    int wid = tid >> 6, lane = tid & 63;
    int cell = blockIdx.x * 16 + wid;
    {
        int ixc = cell >> 6, iyc = cell & 63;
        float lox = (float)ixc * (1.0f / GRIDN);
        float hix = (float)(ixc + 1) * (1.0f / GRIDN);
        float loy = (float)iyc * (1.0f / GRIDN);
        float hiy = (float)(iyc + 1) * (1.0f / GRIDN);
        int total = 0;
        int* row = etab + (size_t)cell * EROW;
        for (int base = 0; base < nprim; base += 64) {
            int p = base + lane;
            bool ov = false;
            if (p < nprim) {
                float4 bb = saabb[p];
                ov = (bb.x < hix) && (bb.y >= lox) && (bb.z < hiy) && (bb.w >= loy);
            }
            unsigned long long m = __ballot(ov);
            if (ov) {
                int pos = total + (int)__popcll(m & ((1ull << lane) - 1ull));
                if (pos < MAXE) { row[1 + pos] = p; srows[wid][1 + pos] = p; }
            }
            total += (int)__popcll(m);
        }
        if (lane == 0) {
            int c = total < MAXE ? total : MAXE;
            row[0] = c;
            srows[wid][0] = c;
        }
    }
    __syncthreads();

    // ---- phase C: subcell pruning (threads 0-255, one subcell each) ----
    if (tid < 256) {
        int lp = tid >> 4;
        int sub = tid & 15;
        int pcell = blockIdx.x * 16 + lp;
        int ix = pcell >> 6, iy = pcell & 63;
        int gx = ix * 4 + (sub >> 2), gy = iy * 4 + (sub & 3);
        double clx = (double)gx * (1.0 / 256.0);
        double chx = (double)(gx + 1) * (1.0 / 256.0);
        double cly = (double)gy * (1.0 / 256.0);
        double chy = (double)(gy + 1) * (1.0 / 256.0);
        int cnt = srows[lp][0];
        unsigned short* srow = subtab + (size_t)(gx * 256 + gy) * 16;
        int oc = 0;
        for (int s = 0; s < cnt; ++s) {
            int e = srows[lp][1 + s];
            float4 A = sseg[e];
            double W = (double)sww[e] + 1e-5;
            double lx = clx - W, hx = chx + W, ly = cly - W, hy = chy + W;
            double ax = (double)A.x, ay = (double)A.y;
            double dx = (double)A.z, dy = (double)A.w;
            double t0 = 0.0, t1 = 1.0;
            bool ok = true;
            if (fabs(dx) > 1e-300) {
                double ta = (lx - ax) / dx, tb = (hx - ax) / dx;
                t0 = fmax(t0, fmin(ta, tb));
                t1 = fmin(t1, fmax(ta, tb));
            } else if (ax < lx || ax > hx) ok = false;
            if (ok) {
                if (fabs(dy) > 1e-300) {
                    double ta = (ly - ay) / dy, tb = (hy - ay) / dy;
                    t0 = fmax(t0, fmin(ta, tb));
                    t1 = fmin(t1, fmax(ta, tb));
                } else if (ay < ly || ay > hy) ok = false;
            }
            if (ok && t0 <= t1) {
                if (oc < SCAP2) srow[1 + oc] = (unsigned short)e;
                ++oc;
            }
        }
        int filled = oc < SCAP2 ? oc : SCAP2;
        for (int k = filled; k < SCAP2; ++k) srow[1 + k] = 0;
        srow[0] = (oc <= SCAP2) ? (unsigned short)oc : (unsigned short)SENTV;
    }

    // ---- phase D: prim pack (block 0) ----
    if (blockIdx.x == 0) {
        bool bad = false;
        for (int p = tid; p < nprim; p += 1024) {
            float x0 = cp[p * 6 + 0], y0 = cp[p * 6 + 1];
            float x1 = cp[p * 6 + 2], y1 = cp[p * 6 + 3];
            float w = sw[p];
            float dx = __fsub_rn(x1, x0);
            float dy = __fsub_rn(y1, y0);
            float dd = __fadd_rn(__fmul_rn(dx, dx), __fmul_rn(dy, dy));
            float denom = fmaxf(dd, 1e-12f);
            double inv = 1.0 / (double)denom;
            unsigned wb = __float_as_uint(w);
            bool even = (wb & 1u) == 0u;
            float wn = __uint_as_float(wb + 1u);
            double md = 0.5 * ((double)w + (double)wn);
            double m2 = md * md;
            float Tf = (float)m2;
            if ((double)Tf > m2) Tf = __uint_as_float(__float_as_uint(Tf) - 1u);
            if (!even && (double)Tf == m2) Tf = __uint_as_float(__float_as_uint(Tf) - 1u);
            unsigned long long ib = __double_as_longlong(inv);
            packed2[p * 2 + 0] = make_float4(x0, y0, dx, dy);
            packed2[p * 2 + 1] = make_float4(Tf,
                                             __uint_as_float((unsigned)(ib & 0xffffffffull)),
                                             __uint_as_float((unsigned)(ib >> 32)),
                                             w);
            float opv = op[p];
            colors[p] = make_float4(fc[p * 3 + 0], fc[p * 3 + 1], fc[p * 3 + 2], opv);
            if (opv != 1.0f) bad = true;
        }
        if (bad) atomicOr(&sbad, 1);
        __syncthreads();
        if (tid == 0) flagp[0] = sbad;
    }
}

// sequential exact test (rare paths)
__device__ __forceinline__ void test_seq(int e, float px, float py, bool fast,
                                         int& win, float& cr, float& cg, float& cb,
                                         const f32x4* sA, const f32x4* sBsk,
                                         const float4* __restrict__ colors) {
    f32x4 A = sA[e];
    f32x4 Bv = sBsk[e + 4];
    CORE_EVAL(A, Bv);
    if (fast) {
        if (s2 <= Bv.x) win = e;
    } else {
        float4 C = colors[e];
        float a = (s2 <= Bv.x) ? C.w : 0.0f;
        float om = __fsub_rn(1.0f, a);
        cr = __fadd_rn(__fmul_rn(cr, om), __fmul_rn(C.x, a));
        cg = __fadd_rn(__fmul_rn(cg, om), __fmul_rn(C.y, a));
        cb = __fadd_rn(__fmul_rn(cb, om), __fmul_rn(C.z, a));
    }
}

// ---------------------------------------------------------------------------
// Kernel 2: render. 2 pts/thread, 512-thread blocks. Branchless 4-slot
// groups; ALL 8 ds_read_b128 results pinned live via empty inline-asm
// register ties (ext_vector operands) BEFORE any eval — the compiler must
// issue the loads back-to-back and cannot re-sink them (rounds 9/10/14
// evidence: it otherwise serializes, VGPR_Count 16-32).
// ---------------------------------------------------------------------------
__global__ __launch_bounds__(512) void render_ilp(const float4* __restrict__ xs4,
                                                  const float4* __restrict__ packed2,
                                                  const float4* __restrict__ colors,
                                                  const int* __restrict__ etab,
                                                  const int* __restrict__ subtab,
                                                  const float* __restrict__ bg,
                                                  const int* __restrict__ flagp,
                                                  float* __restrict__ out,
                                                  int n, int nprim) {
    __shared__ f32x4 sA[MAXPRIM];
    __shared__ f32x4 sBsk[MAXPRIM + 4];

    int tid = threadIdx.x;
    long long g0 = (long long)blockIdx.x * 1024 + (long long)tid * 2;
    bool v0 = g0 < (long long)n, v1 = (g0 + 1) < (long long)n;

    float4 P = make_float4(0.f, 0.f, 0.f, 0.f);
    if (v1) {
        P = xs4[g0 >> 1];
    } else if (v0) {
        float2 t2 = ((const float2*)xs4)[g0];
        P.x = t2.x; P.y = t2.y;
    }
    float pxa[2] = {P.x, P.z};
    float pya[2] = {P.y, P.w};
    bool vs[2] = {v0, v1};
    int par[2] = {0, 0};
    i32x4 lo[2], hi[2];
    const int* srowp[2];
    lo[0] = lo[1] = (i32x4){0, 0, 0, 0};
    hi[0] = hi[1] = (i32x4){0, 0, 0, 0};
    srowp[0] = srowp[1] = subtab;

#pragma unroll
    for (int j = 0; j < 2; ++j) {
        if (vs[j]) {
            float px = pxa[j], py = pya[j];
            int ix = (int)__fmul_rn(px, (float)GRIDN);
            ix = min(max(ix, 0), GRIDN - 1);
            int iy = (int)__fmul_rn(py, (float)GRIDN);
            iy = min(max(iy, 0), GRIDN - 1);
            par[j] = ix * GRIDN + iy;
            int sx = (int)__fmul_rn(px, 256.0f) - ix * 4; sx = min(max(sx, 0), 3);
            int sy = (int)__fmul_rn(py, 256.0f) - iy * 4; sy = min(max(sy, 0), 3);
            const int* srow = subtab + (size_t)((ix * 4 + sx) * 256 + (iy * 4 + sy)) * 8;
            srowp[j] = srow;
            lo[j] = ((const i32x4*)srow)[0];
            hi[j] = ((const i32x4*)srow)[1];
        }
    }
    // pin both 32B row taps in flight together
    asm volatile("" : "+v"(lo[0]), "+v"(hi[0]), "+v"(lo[1]), "+v"(hi[1]));

    for (int t = tid; t < nprim; t += 512) {
        sA[t] = ((const f32x4*)packed2)[t * 2 + 0];
        sBsk[t + 4] = ((const f32x4*)packed2)[t * 2 + 1];
    }
    __syncthreads();

    bool fast = (flagp[0] == 0);
    float bgr = bg[0], bgg = bg[1], bgb = bg[2];
    float res[6];

// branchless 4-slot group: 8 ds_read_b128 pinned live before evals
#define FGRP4(basek, ea, eb, ec, ed)                                           \
    {                                                                          \
        f32x4 A0 = sA[ea], Q0 = sBsk[(ea) + 4];                                \
        f32x4 A1 = sA[eb], Q1 = sBsk[(eb) + 4];                                \
        f32x4 A2 = sA[ec], Q2 = sBsk[(ec) + 4];                                \
        f32x4 A3 = sA[ed], Q3 = sBsk[(ed) + 4];                                \
        asm volatile("" : "+v"(A0), "+v"(Q0), "+v"(A1), "+v"(Q1),              \
                          "+v"(A2), "+v"(Q2), "+v"(A3), "+v"(Q3));             \
        { CORE_EVAL(A0, Q0); if (s2 <= Q0.x && (basek) + 0 < cnt) win = (ea); }\
        { CORE_EVAL(A1, Q1); if (s2 <= Q1.x && (basek) + 1 < cnt) win = (eb); }\
        { CORE_EVAL(A2, Q2); if (s2 <= Q2.x && (basek) + 2 < cnt) win = (ec); }\
        { CORE_EVAL(A3, Q3); if (s2 <= Q3.x && (basek) + 3 < cnt) win = (ed); }\
    }
#define FGRP3(basek, ea, eb, ec)                                               \
    {                                                                          \
        f32x4 A0 = sA[ea], Q0 = sBsk[(ea) + 4];                                \
        f32x4 A1 = sA[eb], Q1 = sBsk[(eb) + 4];                                \
        f32x4 A2 = sA[ec], Q2 = sBsk[(ec) + 4];                                \
        asm volatile("" : "+v"(A0), "+v"(Q0), "+v"(A1), "+v"(Q1),              \
                          "+v"(A2), "+v"(Q2));                                 \
        { CORE_EVAL(A0, Q0); if (s2 <= Q0.x && (basek) + 0 < cnt) win = (ea); }\
        { CORE_EVAL(A1, Q1); if (s2 <= Q1.x && (basek) + 1 < cnt) win = (eb); }\
        { CORE_EVAL(A2, Q2); if (s2 <= Q2.x && (basek) + 2 < cnt) win = (ec); }\
    }

#pragma unroll
    for (int j = 0; j < 2; ++j) {
        float px = pxa[j], py = pya[j];
        float cr = bgr, cg = bgg, cb = bgb;
        int win = -1;
        unsigned lx = (unsigned)lo[j].x, ly = (unsigned)lo[j].y;
        unsigned lz = (unsigned)lo[j].z, lw = (unsigned)lo[j].w;
        unsigned hxv = (unsigned)hi[j].x, hyv = (unsigned)hi[j].y;
        unsigned hzv = (unsigned)hi[j].z, hwv = (unsigned)hi[j].w;
        int cnt = vs[j] ? (int)(lx & 0xffffu) : 0;
        if (cnt != SENTV) {
            if (fast) {
                int e0 = (int)(lx >> 16), e1 = (int)(ly & 0xffffu);
                int e2 = (int)(ly >> 16), e3 = (int)(lz & 0xffffu);
                if (cnt > 0) FGRP4(0, e0, e1, e2, e3);
                if (cnt > 4) {
                    int e4 = (int)(lz >> 16), e5 = (int)(lw & 0xffffu);
                    int e6 = (int)(lw >> 16), e7 = (int)(hxv & 0xffffu);
                    FGRP4(4, e4, e5, e6, e7);
                }
                if (cnt > 8) {
                    int e8 = (int)(hxv >> 16), e9 = (int)(hyv & 0xffffu);
                    int e10 = (int)(hyv >> 16), e11 = (int)(hzv & 0xffffu);
                    FGRP4(8, e8, e9, e10, e11);
                }
                if (cnt > 12) {
                    int e12 = (int)(hzv >> 16), e13 = (int)(hwv & 0xffffu);
                    int e14 = (int)(hwv >> 16);
                    FGRP3(12, e12, e13, e14);
                }
            } else {
                const unsigned short* sr16 = (const unsigned short*)srowp[j];
                for (int s = 0; s < cnt; ++s)
                    test_seq((int)sr16[1 + s], px, py, false, win, cr, cg, cb,
                             sA, sBsk, colors);
            }
        } else {
            const int* prow = etab + (size_t)par[j] * EROW;
            int pcnt = prow[0];
            for (int s = 0; s < pcnt; ++s)
                test_seq(prow[1 + s], px, py, fast, win, cr, cg, cb,
                         sA, sBsk, colors);
        }
        if (fast && win >= 0) {
            float4 C = colors[win];
            cr = C.x; cg = C.y; cb = C.z;
        }
        res[j * 3 + 0] = cr;
        res[j * 3 + 1] = cg;
        res[j * 3 + 2] = cb;
    }
#undef FGRP4
#undef FGRP3

    float* ob = out + g0 * 3;
    if (v1) {
        *(float2*)(ob + 0) = make_float2(res[0], res[1]);
        *(float2*)(ob + 2) = make_float2(res[2], res[3]);
        *(float2*)(ob + 4) = make_float2(res[4], res[5]);
    } else if (v0) {
        ob[0] = res[0]; ob[1] = res[1]; ob[2] = res[2];
    }
}

// ---------------------------------------------------------------------------
// Fallback render (parent lists, LDS-staged) if ws_size too small.
// ---------------------------------------------------------------------------
__global__ __launch_bounds__(1024) void render_fb(const float2* __restrict__ xs,
                                                  const float4* __restrict__ packed2,
                                                  const float4* __restrict__ colors,
                                                  const int* __restrict__ etab,
                                                  const float* __restrict__ bg,
                                                  float* __restrict__ out, int n, int nprim) {
    __shared__ f32x4 sA[MAXPRIM];
    __shared__ f32x4 sBsk[MAXPRIM + 4];
    __shared__ int sflag;
    if (threadIdx.x == 0) sflag = 0;
    __syncthreads();

    int i = blockIdx.x * 1024 + threadIdx.x;
    bool valid = i < n;
    float px = 0.0f, py = 0.0f;
    int row = 0;
    int4 c0 = make_int4(0, 0, 0, 0), c1 = make_int4(0, 0, 0, 0);
    if (valid) {
        float2 pxy = xs[i];
        px = pxy.x; py = pxy.y;
        int ix = (int)__fmul_rn(px, (float)GRIDN);
        ix = min(max(ix, 0), GRIDN - 1);
        int iy = (int)__fmul_rn(py, (float)GRIDN);
        iy = min(max(iy, 0), GRIDN - 1);
        row = (ix * GRIDN + iy) * EROW;
        c0 = *(const int4*)(etab + row);
        c1 = *(const int4*)(etab + row + 4);
    }
    for (int t = threadIdx.x; t < nprim; t += 1024) {
        sA[t] = ((const f32x4*)packed2)[t * 2 + 0];
        sBsk[t + 4] = ((const f32x4*)packed2)[t * 2 + 1];
        if (colors[t].w != 1.0f) sflag = 1;
    }
    __syncthreads();
    int cnt = valid ? c0.x : 0;
    float cr = bg[0], cg = bg[1], cb = bg[2];
    int win = -1;
    bool fast = (sflag == 0);
    if (cnt > 0) test_seq(c0.y, px, py, fast, win, cr, cg, cb, sA, sBsk, colors);
    if (cnt > 1) test_seq(c0.z, px, py, fast, win, cr, cg, cb, sA, sBsk, colors);
    if (cnt > 2) test_seq(c0.w, px, py, fast, win, cr, cg, cb, sA, sBsk, colors);
    if (cnt > 3) test_seq(c1.x, px, py, fast, win, cr, cg, cb, sA, sBsk, colors);
    if (cnt > 4) test_seq(c1.y, px, py, fast, win, cr, cg, cb, sA, sBsk, colors);
    if (cnt > 5) test_seq(c1.z, px, py, fast, win, cr, cg, cb, sA, sBsk, colors);
    if (cnt > 6) test_seq(c1.w, px, py, fast, win, cr, cg, cb, sA, sBsk, colors);
    for (int base = 7; base < cnt; base += 4) {
        int4 c = *(const int4*)(etab + row + 1 + base);
        if (base + 0 < cnt) test_seq(c.x, px, py, fast, win, cr, cg, cb, sA, sBsk, colors);
        if (base + 1 < cnt) test_seq(c.y, px, py, fast, win, cr, cg, cb, sA, sBsk, colors);
        if (base + 2 < cnt) test_seq(c.z, px, py, fast, win, cr, cg, cb, sA, sBsk, colors);
        if (base + 3 < cnt) test_seq(c.w, px, py, fast, win, cr, cg, cb, sA, sBsk, colors);
    }
    if (valid) {
        if (fast && win >= 0) {
            float4 C = colors[win];
            cr = C.x; cg = C.y; cb = C.z;
        }
        out[(size_t)i * 3 + 0] = cr;
        out[(size_t)i * 3 + 1] = cg;
        out[(size_t)i * 3 + 2] = cb;
    }
}

extern "C" void kernel_launch(void* const* d_in, const int* in_sizes, int n_in,
                              void* d_out, int out_size, void* d_ws, size_t ws_size,
                              hipStream_t stream) {
    const float* x  = (const float*)d_in[0];
    const float* cp = (const float*)d_in[1];
    const float* sw = (const float*)d_in[2];
    const float* fc = (const float*)d_in[3];
    const float* op = (const float*)d_in[4];
    const float* bg = (const float*)d_in[5];
    float* out = (float*)d_out;

    int npts  = in_sizes[0] / 2;
    int nprim = in_sizes[2];

    char* ws = (char*)d_ws;
    float4* packed2 = (float4*)(ws + WS_PACKED2);
    float4* colors  = (float4*)(ws + WS_COLORS);
    int* etab       = (int*)(ws + WS_ETAB);
    int* flagp      = (int*)(ws + WS_FLAG);
    unsigned short* subtab = (unsigned short*)(ws + WS_SUBTAB);

    size_t need = (size_t)WS_SUBTAB + 65536u * 32u;
    bool use_sub = (ws_size >= need);

    prep2<<<GRIDN * GRIDN / 16, 1024, 0, stream>>>(cp, sw, fc, op, packed2, colors,
                                                   etab, flagp, subtab, nprim);
    if (use_sub) {
        int nblk = (npts + 1023) / 1024;
        render_ilp<<<nblk, 512, 0, stream>>>((const float4*)x, packed2, colors,
                                             etab, (const int*)subtab, bg, flagp,
                                             out, npts, nprim);
    } else {
        render_fb<<<(npts + 1023) / 1024, 1024, 0, stream>>>((const float2*)x, packed2,
                                                             colors, etab, bg, out,
                                                             npts, nprim);
    }
}

// Round 16
// 54.236 us; speedup vs baseline: 8.3382x; 1.0294x over previous
//
#include <hip/hip_runtime.h>
#include <math.h>

#define GRIDN 64
#define MAXE 32
#define MAXPRIM 1024
#define EROW 36        // parent row: [cnt, e0..e31, pad x3]
#define SCAP2 15
#define SENTV 0xFFFF

typedef float f32x4 __attribute__((ext_vector_type(4)));
typedef int   i32x4 __attribute__((ext_vector_type(4)));

// workspace layout (bytes)
#define WS_PACKED2   0u            // 1024*32
#define WS_COLORS    32768u        // 1024*16
#define WS_ETAB      49152u        // 4096*36*4 -> ends 638976
#define WS_FLAG      638976u       // 4 B: nonzero if any opacity != 1
#define WS_SUBTAB    655360u       // 65536*32 = 2 MB -> ends 2752512

// exact core: t = rn(td/denom) (double-recip mul), s2 <= Tf <=> rn(sqrt(s2)) <= w
#define CORE_EVAL(A, Bv)                                                         \
    float relx = __fsub_rn(px, (A).x);                                           \
    float rely = __fsub_rn(py, (A).y);                                           \
    float td = __fadd_rn(__fmul_rn(relx, (A).z), __fmul_rn(rely, (A).w));        \
    double inv = __hiloint2double(__float_as_int((Bv).z), __float_as_int((Bv).y)); \
    float tt = (float)((double)td * inv);                                        \
    tt = fminf(fmaxf(tt, 0.0f), 1.0f);                                           \
    float qx = __fsub_rn(relx, __fmul_rn(tt, (A).z));                            \
    float qy = __fsub_rn(rely, __fmul_rn(tt, (A).w));                            \
    float s2 = __fadd_rn(__fmul_rn(qx, qx), __fmul_rn(qy, qy));

// ---------------------------------------------------------------------------
// Kernel 1 (fused): parent grid build + subgrid prune + (block 0) prim pack.
// ---------------------------------------------------------------------------
__global__ __launch_bounds__(1024) void prep2(const float* __restrict__ cp,
                                              const float* __restrict__ sw,
                                              const float* __restrict__ fc,
                                              const float* __restrict__ op,
                                              float4* __restrict__ packed2,
                                              float4* __restrict__ colors,
                                              int* __restrict__ etab,
                                              int* __restrict__ flagp,
                                              unsigned short* __restrict__ subtab,
                                              int nprim) {
    __shared__ float4 saabb[MAXPRIM];
    __shared__ float4 sseg[MAXPRIM];   // (x0, y0, dx, dy)
    __shared__ float  sww[MAXPRIM];
    __shared__ int    srows[16][EROW];
    __shared__ int    sbad;
    int tid = threadIdx.x;
    if (tid == 0) sbad = 0;
    for (int p = tid; p < nprim; p += 1024) {
        float x0 = cp[p * 6 + 0], y0 = cp[p * 6 + 1];
        float x1 = cp[p * 6 + 2], y1 = cp[p * 6 + 3];
        float w = sw[p];
        saabb[p] = make_float4(__fsub_rn(fminf(x0, x1), w), __fadd_rn(fmaxf(x0, x1), w),
                               __fsub_rn(fminf(y0, y1), w), __fadd_rn(fmaxf(y0, y1), w));
        sseg[p] = make_float4(x0, y0, __fsub_rn(x1, x0), __fsub_rn(y1, y0));
        sww[p] = w;
    }
    __syncthreads();

    // ---- phase B: parent rows (one wave per parent cell) ----
    int wid = tid >> 6, lane = tid & 63;
    int cell = blockIdx.x * 16 + wid;
    {
        int ixc = cell >> 6, iyc = cell & 63;
        float lox = (float)ixc * (1.0f / GRIDN);
        float hix = (float)(ixc + 1) * (1.0f / GRIDN);
        float loy = (float)iyc * (1.0f / GRIDN);
        float hiy = (float)(iyc + 1) * (1.0f / GRIDN);
        int total = 0;
        int* row = etab + (size_t)cell * EROW;
        for (int base = 0; base < nprim; base += 64) {
            int p = base + lane;
            bool ov = false;
            if (p < nprim) {
                float4 bb = saabb[p];
                ov = (bb.x < hix) && (bb.y >= lox) && (bb.z < hiy) && (bb.w >= loy);
            }
            unsigned long long m = __ballot(ov);
            if (ov) {
                int pos = total + (int)__popcll(m & ((1ull << lane) - 1ull));
                if (pos < MAXE) { row[1 + pos] = p; srows[wid][1 + pos] = p; }
            }
            total += (int)__popcll(m);
        }
        if (lane == 0) {
            int c = total < MAXE ? total : MAXE;
            row[0] = c;
            srows[wid][0] = c;
        }
    }
    __syncthreads();

    // ---- phase C: subcell pruning (threads 0-255, one subcell each) ----
    if (tid < 256) {
        int lp = tid >> 4;
        int sub = tid & 15;
        int pcell = blockIdx.x * 16 + lp;
        int ix = pcell >> 6, iy = pcell & 63;
        int gx = ix * 4 + (sub >> 2), gy = iy * 4 + (sub & 3);
        double clx = (double)gx * (1.0 / 256.0);
        double chx = (double)(gx + 1) * (1.0 / 256.0);
        double cly = (double)gy * (1.0 / 256.0);
        double chy = (double)(gy + 1) * (1.0 / 256.0);
        int cnt = srows[lp][0];
        unsigned short* srow = subtab + (size_t)(gx * 256 + gy) * 16;
        int oc = 0;
        for (int s = 0; s < cnt; ++s) {
            int e = srows[lp][1 + s];
            float4 A = sseg[e];
            double W = (double)sww[e] + 1e-5;
            double lx = clx - W, hx = chx + W, ly = cly - W, hy = chy + W;
            double ax = (double)A.x, ay = (double)A.y;
            double dx = (double)A.z, dy = (double)A.w;
            double t0 = 0.0, t1 = 1.0;
            bool ok = true;
            if (fabs(dx) > 1e-300) {
                double ta = (lx - ax) / dx, tb = (hx - ax) / dx;
                t0 = fmax(t0, fmin(ta, tb));
                t1 = fmin(t1, fmax(ta, tb));
            } else if (ax < lx || ax > hx) ok = false;
            if (ok) {
                if (fabs(dy) > 1e-300) {
                    double ta = (ly - ay) / dy, tb = (hy - ay) / dy;
                    t0 = fmax(t0, fmin(ta, tb));
                    t1 = fmin(t1, fmax(ta, tb));
                } else if (ay < ly || ay > hy) ok = false;
            }
            if (ok && t0 <= t1) {
                if (oc < SCAP2) srow[1 + oc] = (unsigned short)e;
                ++oc;
            }
        }
        int filled = oc < SCAP2 ? oc : SCAP2;
        for (int k = filled; k < SCAP2; ++k) srow[1 + k] = 0;
        srow[0] = (oc <= SCAP2) ? (unsigned short)oc : (unsigned short)SENTV;
    }

    // ---- phase D: prim pack (block 0) ----
    if (blockIdx.x == 0) {
        bool bad = false;
        for (int p = tid; p < nprim; p += 1024) {
            float x0 = cp[p * 6 + 0], y0 = cp[p * 6 + 1];
            float x1 = cp[p * 6 + 2], y1 = cp[p * 6 + 3];
            float w = sw[p];
            float dx = __fsub_rn(x1, x0);
            float dy = __fsub_rn(y1, y0);
            float dd = __fadd_rn(__fmul_rn(dx, dx), __fmul_rn(dy, dy));
            float denom = fmaxf(dd, 1e-12f);
            double inv = 1.0 / (double)denom;
            unsigned wb = __float_as_uint(w);
            bool even = (wb & 1u) == 0u;
            float wn = __uint_as_float(wb + 1u);
            double md = 0.5 * ((double)w + (double)wn);
            double m2 = md * md;
            float Tf = (float)m2;
            if ((double)Tf > m2) Tf = __uint_as_float(__float_as_uint(Tf) - 1u);
            if (!even && (double)Tf == m2) Tf = __uint_as_float(__float_as_uint(Tf) - 1u);
            unsigned long long ib = __double_as_longlong(inv);
            packed2[p * 2 + 0] = make_float4(x0, y0, dx, dy);
            packed2[p * 2 + 1] = make_float4(Tf,
                                             __uint_as_float((unsigned)(ib & 0xffffffffull)),
                                             __uint_as_float((unsigned)(ib >> 32)),
                                             w);
            float opv = op[p];
            colors[p] = make_float4(fc[p * 3 + 0], fc[p * 3 + 1], fc[p * 3 + 2], opv);
            if (opv != 1.0f) bad = true;
        }
        if (bad) atomicOr(&sbad, 1);
        __syncthreads();
        if (tid == 0) flagp[0] = sbad;
    }
}

// sequential exact test (rare paths)
__device__ __forceinline__ void test_seq(int e, float px, float py, bool fast,
                                         int& win, float& cr, float& cg, float& cb,
                                         const f32x4* sA, const f32x4* sBsk,
                                         const float4* __restrict__ colors) {
    f32x4 A = sA[e];
    f32x4 Bv = sBsk[e + 4];
    CORE_EVAL(A, Bv);
    if (fast) {
        if (s2 <= Bv.x) win = e;
    } else {
        float4 C = colors[e];
        float a = (s2 <= Bv.x) ? C.w : 0.0f;
        float om = __fsub_rn(1.0f, a);
        cr = __fadd_rn(__fmul_rn(cr, om), __fmul_rn(C.x, a));
        cg = __fadd_rn(__fmul_rn(cg, om), __fmul_rn(C.y, a));
        cb = __fadd_rn(__fmul_rn(cb, om), __fmul_rn(C.z, a));
    }
}

// ---------------------------------------------------------------------------
// Kernel 2: render. 2 pts/thread, 512-thread blocks. Branchless 4-slot
// groups, predicated winner updates. (Round-11 configuration — measured
// session best 53.05 µs; asm pins removed: they raised VGPR 32->44 and
// halved occupancy for zero time gain, rounds 14-15.)
// ---------------------------------------------------------------------------
__global__ __launch_bounds__(512) void render_ilp(const float4* __restrict__ xs4,
                                                  const float4* __restrict__ packed2,
                                                  const float4* __restrict__ colors,
                                                  const int* __restrict__ etab,
                                                  const int* __restrict__ subtab,
                                                  const float* __restrict__ bg,
                                                  const int* __restrict__ flagp,
                                                  float* __restrict__ out,
                                                  int n, int nprim) {
    __shared__ f32x4 sA[MAXPRIM];
    __shared__ f32x4 sBsk[MAXPRIM + 4];

    int tid = threadIdx.x;
    long long g0 = (long long)blockIdx.x * 1024 + (long long)tid * 2;
    bool v0 = g0 < (long long)n, v1 = (g0 + 1) < (long long)n;

    float4 P = make_float4(0.f, 0.f, 0.f, 0.f);
    if (v1) {
        P = xs4[g0 >> 1];
    } else if (v0) {
        float2 t2 = ((const float2*)xs4)[g0];
        P.x = t2.x; P.y = t2.y;
    }
    float pxa[2] = {P.x, P.z};
    float pya[2] = {P.y, P.w};
    bool vs[2] = {v0, v1};
    int par[2] = {0, 0};
    i32x4 lo[2], hi[2];
    const int* srowp[2];
    lo[0] = lo[1] = (i32x4){0, 0, 0, 0};
    hi[0] = hi[1] = (i32x4){0, 0, 0, 0};
    srowp[0] = srowp[1] = subtab;

#pragma unroll
    for (int j = 0; j < 2; ++j) {
        if (vs[j]) {
            float px = pxa[j], py = pya[j];
            int ix = (int)__fmul_rn(px, (float)GRIDN);
            ix = min(max(ix, 0), GRIDN - 1);
            int iy = (int)__fmul_rn(py, (float)GRIDN);
            iy = min(max(iy, 0), GRIDN - 1);
            par[j] = ix * GRIDN + iy;
            int sx = (int)__fmul_rn(px, 256.0f) - ix * 4; sx = min(max(sx, 0), 3);
            int sy = (int)__fmul_rn(py, 256.0f) - iy * 4; sy = min(max(sy, 0), 3);
            const int* srow = subtab + (size_t)((ix * 4 + sx) * 256 + (iy * 4 + sy)) * 8;
            srowp[j] = srow;
            lo[j] = ((const i32x4*)srow)[0];
            hi[j] = ((const i32x4*)srow)[1];
        }
    }

    for (int t = tid; t < nprim; t += 512) {
        sA[t] = ((const f32x4*)packed2)[t * 2 + 0];
        sBsk[t + 4] = ((const f32x4*)packed2)[t * 2 + 1];
    }
    __syncthreads();

    bool fast = (flagp[0] == 0);
    float bgr = bg[0], bgg = bg[1], bgb = bg[2];
    float res[6];

// branchless 4-slot group: loads first, predicated winner updates
#define FGRP4(basek, ea, eb, ec, ed)                                           \
    {                                                                          \
        f32x4 A0 = sA[ea], Q0 = sBsk[(ea) + 4];                                \
        f32x4 A1 = sA[eb], Q1 = sBsk[(eb) + 4];                                \
        f32x4 A2 = sA[ec], Q2 = sBsk[(ec) + 4];                                \
        f32x4 A3 = sA[ed], Q3 = sBsk[(ed) + 4];                                \
        { CORE_EVAL(A0, Q0); if (s2 <= Q0.x && (basek) + 0 < cnt) win = (ea); }\
        { CORE_EVAL(A1, Q1); if (s2 <= Q1.x && (basek) + 1 < cnt) win = (eb); }\
        { CORE_EVAL(A2, Q2); if (s2 <= Q2.x && (basek) + 2 < cnt) win = (ec); }\
        { CORE_EVAL(A3, Q3); if (s2 <= Q3.x && (basek) + 3 < cnt) win = (ed); }\
    }
#define FGRP3(basek, ea, eb, ec)                                               \
    {                                                                          \
        f32x4 A0 = sA[ea], Q0 = sBsk[(ea) + 4];                                \
        f32x4 A1 = sA[eb], Q1 = sBsk[(eb) + 4];                                \
        f32x4 A2 = sA[ec], Q2 = sBsk[(ec) + 4];                                \
        { CORE_EVAL(A0, Q0); if (s2 <= Q0.x && (basek) + 0 < cnt) win = (ea); }\
        { CORE_EVAL(A1, Q1); if (s2 <= Q1.x && (basek) + 1 < cnt) win = (eb); }\
        { CORE_EVAL(A2, Q2); if (s2 <= Q2.x && (basek) + 2 < cnt) win = (ec); }\
    }

#pragma unroll
    for (int j = 0; j < 2; ++j) {
        float px = pxa[j], py = pya[j];
        float cr = bgr, cg = bgg, cb = bgb;
        int win = -1;
        unsigned lx = (unsigned)lo[j].x, ly = (unsigned)lo[j].y;
        unsigned lz = (unsigned)lo[j].z, lw = (unsigned)lo[j].w;
        unsigned hxv = (unsigned)hi[j].x, hyv = (unsigned)hi[j].y;
        unsigned hzv = (unsigned)hi[j].z, hwv = (unsigned)hi[j].w;
        int cnt = vs[j] ? (int)(lx & 0xffffu) : 0;
        if (cnt != SENTV) {
            if (fast) {
                int e0 = (int)(lx >> 16), e1 = (int)(ly & 0xffffu);
                int e2 = (int)(ly >> 16), e3 = (int)(lz & 0xffffu);
                if (cnt > 0) FGRP4(0, e0, e1, e2, e3);
                if (cnt > 4) {
                    int e4 = (int)(lz >> 16), e5 = (int)(lw & 0xffffu);
                    int e6 = (int)(lw >> 16), e7 = (int)(hxv & 0xffffu);
                    FGRP4(4, e4, e5, e6, e7);
                }
                if (cnt > 8) {
                    int e8 = (int)(hxv >> 16), e9 = (int)(hyv & 0xffffu);
                    int e10 = (int)(hyv >> 16), e11 = (int)(hzv & 0xffffu);
                    FGRP4(8, e8, e9, e10, e11);
                }
                if (cnt > 12) {
                    int e12 = (int)(hzv >> 16), e13 = (int)(hwv & 0xffffu);
                    int e14 = (int)(hwv >> 16);
                    FGRP3(12, e12, e13, e14);
                }
            } else {
                const unsigned short* sr16 = (const unsigned short*)srowp[j];
                for (int s = 0; s < cnt; ++s)
                    test_seq((int)sr16[1 + s], px, py, false, win, cr, cg, cb,
                             sA, sBsk, colors);
            }
        } else {
            const int* prow = etab + (size_t)par[j] * EROW;
            int pcnt = prow[0];
            for (int s = 0; s < pcnt; ++s)
                test_seq(prow[1 + s], px, py, fast, win, cr, cg, cb,
                         sA, sBsk, colors);
        }
        if (fast && win >= 0) {
            float4 C = colors[win];
            cr = C.x; cg = C.y; cb = C.z;
        }
        res[j * 3 + 0] = cr;
        res[j * 3 + 1] = cg;
        res[j * 3 + 2] = cb;
    }
#undef FGRP4
#undef FGRP3

    float* ob = out + g0 * 3;
    if (v1) {
        *(float2*)(ob + 0) = make_float2(res[0], res[1]);
        *(float2*)(ob + 2) = make_float2(res[2], res[3]);
        *(float2*)(ob + 4) = make_float2(res[4], res[5]);
    } else if (v0) {
        ob[0] = res[0]; ob[1] = res[1]; ob[2] = res[2];
    }
}

// ---------------------------------------------------------------------------
// Fallback render (parent lists, LDS-staged) if ws_size too small.
// ---------------------------------------------------------------------------
__global__ __launch_bounds__(1024) void render_fb(const float2* __restrict__ xs,
                                                  const float4* __restrict__ packed2,
                                                  const float4* __restrict__ colors,
                                                  const int* __restrict__ etab,
                                                  const float* __restrict__ bg,
                                                  float* __restrict__ out, int n, int nprim) {
    __shared__ f32x4 sA[MAXPRIM];
    __shared__ f32x4 sBsk[MAXPRIM + 4];
    __shared__ int sflag;
    if (threadIdx.x == 0) sflag = 0;
    __syncthreads();

    int i = blockIdx.x * 1024 + threadIdx.x;
    bool valid = i < n;
    float px = 0.0f, py = 0.0f;
    int row = 0;
    int4 c0 = make_int4(0, 0, 0, 0), c1 = make_int4(0, 0, 0, 0);
    if (valid) {
        float2 pxy = xs[i];
        px = pxy.x; py = pxy.y;
        int ix = (int)__fmul_rn(px, (float)GRIDN);
        ix = min(max(ix, 0), GRIDN - 1);
        int iy = (int)__fmul_rn(py, (float)GRIDN);
        iy = min(max(iy, 0), GRIDN - 1);
        row = (ix * GRIDN + iy) * EROW;
        c0 = *(const int4*)(etab + row);
        c1 = *(const int4*)(etab + row + 4);
    }
    for (int t = threadIdx.x; t < nprim; t += 1024) {
        sA[t] = ((const f32x4*)packed2)[t * 2 + 0];
        sBsk[t + 4] = ((const f32x4*)packed2)[t * 2 + 1];
        if (colors[t].w != 1.0f) sflag = 1;
    }
    __syncthreads();
    int cnt = valid ? c0.x : 0;
    float cr = bg[0], cg = bg[1], cb = bg[2];
    int win = -1;
    bool fast = (sflag == 0);
    if (cnt > 0) test_seq(c0.y, px, py, fast, win, cr, cg, cb, sA, sBsk, colors);
    if (cnt > 1) test_seq(c0.z, px, py, fast, win, cr, cg, cb, sA, sBsk, colors);
    if (cnt > 2) test_seq(c0.w, px, py, fast, win, cr, cg, cb, sA, sBsk, colors);
    if (cnt > 3) test_seq(c1.x, px, py, fast, win, cr, cg, cb, sA, sBsk, colors);
    if (cnt > 4) test_seq(c1.y, px, py, fast, win, cr, cg, cb, sA, sBsk, colors);
    if (cnt > 5) test_seq(c1.z, px, py, fast, win, cr, cg, cb, sA, sBsk, colors);
    if (cnt > 6) test_seq(c1.w, px, py, fast, win, cr, cg, cb, sA, sBsk, colors);
    for (int base = 7; base < cnt; base += 4) {
        int4 c = *(const int4*)(etab + row + 1 + base);
        if (base + 0 < cnt) test_seq(c.x, px, py, fast, win, cr, cg, cb, sA, sBsk, colors);
        if (base + 1 < cnt) test_seq(c.y, px, py, fast, win, cr, cg, cb, sA, sBsk, colors);
        if (base + 2 < cnt) test_seq(c.z, px, py, fast, win, cr, cg, cb, sA, sBsk, colors);
        if (base + 3 < cnt) test_seq(c.w, px, py, fast, win, cr, cg, cb, sA, sBsk, colors);
    }
    if (valid) {
        if (fast && win >= 0) {
            float4 C = colors[win];
            cr = C.x; cg = C.y; cb = C.z;
        }
        out[(size_t)i * 3 + 0] = cr;
        out[(size_t)i * 3 + 1] = cg;
        out[(size_t)i * 3 + 2] = cb;
    }
}

extern "C" void kernel_launch(void* const* d_in, const int* in_sizes, int n_in,
                              void* d_out, int out_size, void* d_ws, size_t ws_size,
                              hipStream_t stream) {
    const float* x  = (const float*)d_in[0];
    const float* cp = (const float*)d_in[1];
    const float* sw = (const float*)d_in[2];
    const float* fc = (const float*)d_in[3];
    const float* op = (const float*)d_in[4];
    const float* bg = (const float*)d_in[5];
    float* out = (float*)d_out;

    int npts  = in_sizes[0] / 2;
    int nprim = in_sizes[2];

    char* ws = (char*)d_ws;
    float4* packed2 = (float4*)(ws + WS_PACKED2);
    float4* colors  = (float4*)(ws + WS_COLORS);
    int* etab       = (int*)(ws + WS_ETAB);
    int* flagp      = (int*)(ws + WS_FLAG);
    unsigned short* subtab = (unsigned short*)(ws + WS_SUBTAB);

    size_t need = (size_t)WS_SUBTAB + 65536u * 32u;
    bool use_sub = (ws_size >= need);

    prep2<<<GRIDN * GRIDN / 16, 1024, 0, stream>>>(cp, sw, fc, op, packed2, colors,
                                                   etab, flagp, subtab, nprim);
    if (use_sub) {
        int nblk = (npts + 1023) / 1024;
        render_ilp<<<nblk, 512, 0, stream>>>((const float4*)x, packed2, colors,
                                             etab, (const int*)subtab, bg, flagp,
                                             out, npts, nprim);
    } else {
        render_fb<<<(npts + 1023) / 1024, 1024, 0, stream>>>((const float2*)x, packed2,
                                                             colors, etab, bg, out,
                                                             npts, nprim);
    }
}